// Round 12
// baseline (316.389 us; speedup 1.0000x reference)
//
#include <hip/hip_runtime.h>

#define BB 32
#define NN 512
#define FF 128
#define K4 2048
#define ALPHA 0.2f
#define THRESH 0.6f
#define NEGINF -9e15f

typedef unsigned short u16;
typedef unsigned int u32;
typedef _Float16 f16;
typedef __attribute__((ext_vector_type(8))) _Float16 half8;
typedef __attribute__((ext_vector_type(4))) float f32x4;

union U16F { u16 u; f16 h; };
__device__ __forceinline__ u16 hbits(f16 h) { U16F x; x.h = h; return x.u; }
__device__ __forceinline__ float htof(u16 u) { U16F x; x.u = u; return (float)x.h; }
__device__ __forceinline__ void split2(float v, u16& hi, u16& lo) {
    f16 h = (f16)v;
    f16 l = (f16)(v - (float)h);
    hi = hbits(h);
    lo = hbits(l);
}
__device__ __forceinline__ float lrelu(float x) { return fmaxf(x, ALPHA * x); }

__device__ __forceinline__ void gload16(const void* g, void* l) {
    __builtin_amdgcn_global_load_lds(
        (__attribute__((address_space(1))) const unsigned int*)(unsigned long long)g,
        (__attribute__((address_space(3))) unsigned int*)(unsigned int)(unsigned long long)l,
        16, 0, 0);
}

// u1[f] = sum_g W[g,f]*a[g];  u2[f] = sum_g W[g,f]*a[F+g]
__global__ void k_u(const float* __restrict__ W, const float* __restrict__ a,
                    float* __restrict__ u12) {
    int f = threadIdx.x;
    float s1 = 0.f, s2 = 0.f;
    for (int g = 0; g < FF; ++g) {
        float w = W[g * FF + f];
        s1 += w * a[g];
        s2 += w * a[FF + g];
    }
    u12[f] = s1;
    u12[FF + f] = s2;
}

// Wh1[row] = h[row,:]·u1 ; Wh2[row] = h[row,:]·u2   (flat row = b*N+n)
__global__ void k_wh12(const float* __restrict__ h, const float* __restrict__ u12,
                       float* __restrict__ Wh12) {
    int row = blockIdx.x;
    int f = threadIdx.x;  // 128
    float hv = h[(size_t)row * FF + f];
    float p1 = hv * u12[f], p2 = hv * u12[FF + f];
#pragma unroll
    for (int o = 1; o < 64; o <<= 1) {
        p1 += __shfl_xor(p1, o, 64);
        p2 += __shfl_xor(p2, o, 64);
    }
    __shared__ float s1[2], s2[2];
    int w = f >> 6;
    if ((f & 63) == 0) { s1[w] = p1; s2[w] = p2; }
    __syncthreads();
    if (f == 0) {
        Wh12[row] = s1[0] + s1[1];
        Wh12[BB * NN + row] = s2[0] + s2[1];
    }
}

// WhT[b][f][n] = (h@W^T)[b][n][f] split into fp16 hi/lo (PV's B operand).
__global__ __launch_bounds__(256) void k_whT(const float* __restrict__ W,
                                             const float* __restrict__ h,
                                             u16* __restrict__ Thi, u16* __restrict__ Tlo) {
    const int bm = blockIdx.y * 64, bn = blockIdx.x * 64;
    __shared__ float As[32][68];
    __shared__ float Bs[32][68];
    int tid = threadIdx.x;
    int tx = tid & 15, ty = tid >> 4;
    float acc[4][4] = {{0.f}};
    int r = tid >> 3, q = tid & 7;
    const float* Ap = W + (size_t)(bm + r) * FF + q * 4;
    const float* Bp = h + (size_t)(bn + r) * FF + q * 4;
    for (int k0 = 0; k0 < FF; k0 += 32) {
        float4 a0 = *(const float4*)(Ap + k0);
        float4 a1 = *(const float4*)(Ap + k0 + 32 * FF);
        float4 b0 = *(const float4*)(Bp + k0);
        float4 b1 = *(const float4*)(Bp + k0 + 32 * FF);
        __syncthreads();
        As[q * 4 + 0][r] = a0.x; As[q * 4 + 1][r] = a0.y;
        As[q * 4 + 2][r] = a0.z; As[q * 4 + 3][r] = a0.w;
        As[q * 4 + 0][r + 32] = a1.x; As[q * 4 + 1][r + 32] = a1.y;
        As[q * 4 + 2][r + 32] = a1.z; As[q * 4 + 3][r + 32] = a1.w;
        Bs[q * 4 + 0][r] = b0.x; Bs[q * 4 + 1][r] = b0.y;
        Bs[q * 4 + 2][r] = b0.z; Bs[q * 4 + 3][r] = b0.w;
        Bs[q * 4 + 0][r + 32] = b1.x; Bs[q * 4 + 1][r + 32] = b1.y;
        Bs[q * 4 + 2][r + 32] = b1.z; Bs[q * 4 + 3][r + 32] = b1.w;
        __syncthreads();
#pragma unroll
        for (int kk = 0; kk < 32; ++kk) {
            float av[4], bv[4];
            *(float4*)av = *(const float4*)&As[kk][ty * 4];
            *(float4*)bv = *(const float4*)&Bs[kk][tx * 4];
#pragma unroll
            for (int i = 0; i < 4; ++i)
#pragma unroll
                for (int j = 0; j < 4; ++j) acc[i][j] = fmaf(av[i], bv[j], acc[i][j]);
        }
    }
#pragma unroll
    for (int i = 0; i < 4; ++i) {
        int f = bm + ty * 4 + i;
#pragma unroll
        for (int j = 0; j < 4; ++j) {
            int mg = bn + tx * 4 + j;
            u16 hi, lo;
            split2(acc[i][j], hi, lo);
            size_t idx = ((size_t)(mg >> 9) * FF + f) * NN + (mg & 511);
            Thi[idx] = hi;
            Tlo[idx] = lo;
        }
    }
}

// fp32 -> fp16 hi/lo split, vectorized
__global__ void k_split(const float* __restrict__ X, u16* __restrict__ Hi,
                        u16* __restrict__ Lo, int n4) {
    int i = blockIdx.x * 256 + threadIdx.x;
    if (i >= n4) return;
    float4 v = *(const float4*)(X + (size_t)i * 4);
    ushort4 hh, ll;
    split2(v.x, hh.x, ll.x);
    split2(v.y, hh.y, ll.y);
    split2(v.z, hh.z, ll.z);
    split2(v.w, hh.w, ll.w);
    *(ushort4*)(Hi + (size_t)i * 4) = hh;
    *(ushort4*)(Lo + (size_t)i * 4) = ll;
}

// GEMM1: S = sigmoid(E @ A0^T), E generated on the fly from Wh12.
// Tile 128x256 (MxN), BK=32, 512 threads (8 waves: 2m x 4n), SINGLE-buffered
// 48KB LDS -> 3 blocks/CU capacity; grid 32*c -> 2 resident blocks/CU.
__global__ __launch_bounds__(512) void k_g1(const float* __restrict__ Wh12, int c0,
                                            const u16* __restrict__ Bhi,
                                            const u16* __restrict__ Blo,
                                            u16* __restrict__ Shi, u16* __restrict__ Slo,
                                            int mblocks) {
    __shared__ __align__(16) u16 ldsA[8192];   // hi [0..4095], lo [4096..8191]
    __shared__ __align__(16) u16 ldsB[16384];  // hi [0..8191], lo [8192..16383]
    __shared__ float wh1s[128];
    __shared__ float wh2s[512];
    const int tid = threadIdx.x;
    const int l = tid & 63, w = tid >> 6;
    const int wm = w >> 2, wn = w & 3;
    const int nwg = gridDim.x, q = nwg >> 3;
    const int wg = (blockIdx.x & 7) * q + (blockIdx.x >> 3);
    const int nb = wg / mblocks, mb = wg % mblocks;
    const int bm = mb * 128, bn = nb * 256;
    const int bglob = c0 + (bm >> 9);

    if (tid < 128) wh1s[tid] = Wh12[(size_t)c0 * NN + bm + tid];
    if (tid < 512) wh2s[tid] = Wh12[BB * NN + (size_t)bglob * NN + tid];

    f32x4 acc[4][4];
#pragma unroll
    for (int m = 0; m < 4; ++m)
#pragma unroll
        for (int n = 0; n < 4; ++n) acc[m][n] = (f32x4){0.f, 0.f, 0.f, 0.f};

    const int gb0 = w * 2, gb1 = w * 2 + 1;
    const size_t rb0 = (size_t)(bn + gb0 * 16 + (l & 15)) * NN + ((l >> 4) * 8);
    const size_t rb1 = (size_t)(bn + gb1 * 16 + (l & 15)) * NN + ((l >> 4) * 8);
    const int arow = (tid >> 6) * 16 + (l & 15);
    const int akc = (l >> 4) * 8;

    __syncthreads();  // wh arrays ready

    const float myw1 = wh1s[arow];

    for (int t = 0; t < 16; ++t) {
        const int k0 = t * 32;
        gload16(Bhi + rb0 + k0, &ldsB[gb0 * 512]);
        gload16(Bhi + rb1 + k0, &ldsB[gb1 * 512]);
        gload16(Blo + rb0 + k0, &ldsB[8192 + gb0 * 512]);
        gload16(Blo + rb1 + k0, &ldsB[8192 + gb1 * 512]);
        {
            const int kc = k0 + akc;
            float w2v[8];
            *(float4*)&w2v[0] = *(const float4*)&wh2s[kc];
            *(float4*)&w2v[4] = *(const float4*)&wh2s[kc + 4];
            u32 hh[4], llv[4];
#pragma unroll
            for (int jj = 0; jj < 4; ++jj) {
                float e0 = lrelu(myw1 + w2v[2 * jj]);
                float e1 = lrelu(myw1 + w2v[2 * jj + 1]);
                u16 h0, l0, h1, l1;
                split2(e0, h0, l0);
                split2(e1, h1, l1);
                hh[jj] = (u32)h0 | ((u32)h1 << 16);
                llv[jj] = (u32)l0 | ((u32)l1 << 16);
            }
            *(uint4*)&ldsA[tid * 8] = make_uint4(hh[0], hh[1], hh[2], hh[3]);
            *(uint4*)&ldsA[4096 + tid * 8] = make_uint4(llv[0], llv[1], llv[2], llv[3]);
        }
        __syncthreads();
        half8 bh[4], bl[4];
#pragma unroll
        for (int n = 0; n < 4; ++n) {
            const int gB = wn * 4 + n;
            bh[n] = *(const half8*)&ldsB[(gB * 64 + l) * 8];
            bl[n] = *(const half8*)&ldsB[8192 + (gB * 64 + l) * 8];
        }
#pragma unroll
        for (int m = 0; m < 4; ++m) {
            const int gA = wm * 4 + m;
            half8 ah = *(const half8*)&ldsA[(gA * 64 + l) * 8];
            half8 al = *(const half8*)&ldsA[4096 + (gA * 64 + l) * 8];
#pragma unroll
            for (int n = 0; n < 4; ++n)
                acc[m][n] = __builtin_amdgcn_mfma_f32_16x16x32_f16(ah, bh[n], acc[m][n], 0, 0, 0);
#pragma unroll
            for (int n = 0; n < 4; ++n)
                acc[m][n] = __builtin_amdgcn_mfma_f32_16x16x32_f16(al, bh[n], acc[m][n], 0, 0, 0);
#pragma unroll
            for (int n = 0; n < 4; ++n)
                acc[m][n] = __builtin_amdgcn_mfma_f32_16x16x32_f16(ah, bl[n], acc[m][n], 0, 0, 0);
        }
        __syncthreads();
    }

    const int lr = (l >> 4) * 4, lc = l & 15;
#pragma unroll
    for (int m = 0; m < 4; ++m) {
#pragma unroll
        for (int n = 0; n < 4; ++n) {
#pragma unroll
            for (int j = 0; j < 4; ++j) {
                const int row = bm + wm * 64 + m * 16 + lr + j;
                const int col = bn + wn * 64 + n * 16 + lc;
                const float s = 1.f / (1.f + __expf(-acc[m][n][j]));
                u16 hi, lo;
                split2(s, hi, lo);
                const size_t idx = (size_t)row * K4 + col;
                Shi[idx] = hi;
                Slo[idx] = lo;
            }
        }
    }
}

// GEMM2 (K-split): PADJ[ks] = S @ A2^T over K-half ks (fp32 partials).
// Tile 128x128, K-half=1024, BK=32 (32 steps), 4 waves (2m x 2n), wave-tile
// 64x64 (48 MFMA/step), SINGLE-buffered 32KB LDS -> 5 blocks/CU capacity.
// Grid = c*4 mb x 2 ks x 4 nb = c*32 blocks -> 2 resident blocks/CU at c=16;
// cross-block wave overlap hides the per-step drain (g1's proven mechanism).
__global__ __launch_bounds__(256) void k_g2(const u16* __restrict__ Ahi,
                                            const u16* __restrict__ Alo,
                                            const u16* __restrict__ Bhi,
                                            const u16* __restrict__ Blo,
                                            float* __restrict__ PADJ, long sK) {
    __shared__ __align__(16) u16 ldsA[8192];  // hi [0..4095], lo [4096..8191]
    __shared__ __align__(16) u16 ldsB[8192];
    const int tid = threadIdx.x;
    const int l = tid & 63, w = tid >> 6;  // 4 waves
    const int wm = w >> 1, wn = w & 1;
    const int nwg = gridDim.x, q = nwg >> 3;
    const int wg = ((int)blockIdx.x & 7) * q + ((int)blockIdx.x >> 3);
    const int nb = wg & 3, ks = (wg >> 2) & 1, mb = wg >> 3;  // nb-inner
    const int bm = mb * 128, bn = nb * 128;
    const int kbase = ks * 1024;

    // staging: wave w owns row-groups {2w, 2w+1} of A and B (8 loads/wave)
    const int g0 = w * 2, g1 = w * 2 + 1;
    const size_t ra0 = (size_t)(bm + g0 * 16 + (l & 15)) * K4 + kbase + ((l >> 4) * 8);
    const size_t ra1 = (size_t)(bm + g1 * 16 + (l & 15)) * K4 + kbase + ((l >> 4) * 8);
    const size_t rb0 = (size_t)(bn + g0 * 16 + (l & 15)) * K4 + kbase + ((l >> 4) * 8);
    const size_t rb1 = (size_t)(bn + g1 * 16 + (l & 15)) * K4 + kbase + ((l >> 4) * 8);

    f32x4 acc[4][4];
#pragma unroll
    for (int m = 0; m < 4; ++m)
#pragma unroll
        for (int n = 0; n < 4; ++n) acc[m][n] = (f32x4){0.f, 0.f, 0.f, 0.f};

    for (int t = 0; t < 32; ++t) {
        const int k0 = t * 32;
        gload16(Ahi + ra0 + k0, &ldsA[g0 * 512]);
        gload16(Ahi + ra1 + k0, &ldsA[g1 * 512]);
        gload16(Alo + ra0 + k0, &ldsA[4096 + g0 * 512]);
        gload16(Alo + ra1 + k0, &ldsA[4096 + g1 * 512]);
        gload16(Bhi + rb0 + k0, &ldsB[g0 * 512]);
        gload16(Bhi + rb1 + k0, &ldsB[g1 * 512]);
        gload16(Blo + rb0 + k0, &ldsB[4096 + g0 * 512]);
        gload16(Blo + rb1 + k0, &ldsB[4096 + g1 * 512]);
        __syncthreads();  // drains vmcnt; tile ready
        half8 bh[4], bl[4];
#pragma unroll
        for (int n = 0; n < 4; ++n) {
            const int gB = wn * 4 + n;
            bh[n] = *(const half8*)&ldsB[(gB * 64 + l) * 8];
            bl[n] = *(const half8*)&ldsB[4096 + (gB * 64 + l) * 8];
        }
#pragma unroll
        for (int m = 0; m < 4; ++m) {
            const int gA = wm * 4 + m;
            half8 ah = *(const half8*)&ldsA[(gA * 64 + l) * 8];
            half8 al = *(const half8*)&ldsA[4096 + (gA * 64 + l) * 8];
#pragma unroll
            for (int n = 0; n < 4; ++n)
                acc[m][n] = __builtin_amdgcn_mfma_f32_16x16x32_f16(ah, bh[n], acc[m][n], 0, 0, 0);
#pragma unroll
            for (int n = 0; n < 4; ++n)
                acc[m][n] = __builtin_amdgcn_mfma_f32_16x16x32_f16(al, bh[n], acc[m][n], 0, 0, 0);
#pragma unroll
            for (int n = 0; n < 4; ++n)
                acc[m][n] = __builtin_amdgcn_mfma_f32_16x16x32_f16(ah, bl[n], acc[m][n], 0, 0, 0);
        }
        __syncthreads();  // protect LDS before next stage
    }

    float* out = PADJ + (size_t)ks * sK;
    const int lr = (l >> 4) * 4, lc = l & 15;
#pragma unroll
    for (int m = 0; m < 4; ++m) {
#pragma unroll
        for (int n = 0; n < 4; ++n) {
#pragma unroll
            for (int j = 0; j < 4; ++j) {
                const int row = bm + wm * 64 + m * 16 + lr + j;
                const int col = bn + wn * 64 + n * 16 + lc;
                out[(size_t)row * NN + col] = acc[m][n][j];
            }
        }
    }
}

// softmax: combine fp32 partials, recompute e, mask, row-softmax, att fp16 hi/lo
__global__ __launch_bounds__(256) void k_softmax2(const float* __restrict__ PADJ, long sK,
                                                  const float* __restrict__ Wh12, int c0,
                                                  u16* __restrict__ Hi, u16* __restrict__ Lo) {
    const size_t row = blockIdx.x;
    const int t = threadIdx.x;
    const float w1v = Wh12[(size_t)c0 * NN + row];
    const int bglob = c0 + (int)(row >> 9);
    const float* wh2p = Wh12 + BB * NN + (size_t)bglob * NN;
    const float* p0 = PADJ + row * NN;
    const float* p1 = PADJ + sK + row * NN;

    float va = p0[t] + p1[t];
    float vb = p0[t + 256] + p1[t + 256];
    float ea = lrelu(w1v + wh2p[t]);
    float eb = lrelu(w1v + wh2p[t + 256]);
    float v0 = (ea + va > THRESH) ? ea : NEGINF;
    float v1 = (eb + vb > THRESH) ? eb : NEGINF;

    float m = fmaxf(v0, v1);
#pragma unroll
    for (int o = 1; o < 64; o <<= 1) m = fmaxf(m, __shfl_xor(m, o, 64));
    __shared__ float red[4], red2[4];
    int w = t >> 6;
    if ((t & 63) == 0) red[w] = m;
    __syncthreads();
    m = fmaxf(fmaxf(red[0], red[1]), fmaxf(red[2], red[3]));
    float e0 = __expf(v0 - m), e1 = __expf(v1 - m);
    float s = e0 + e1;
#pragma unroll
    for (int o = 1; o < 64; o <<= 1) s += __shfl_xor(s, o, 64);
    if ((t & 63) == 0) red2[w] = s;
    __syncthreads();
    s = red2[0] + red2[1] + red2[2] + red2[3];
    float inv = 1.f / s;
    float a0 = e0 * inv, a1 = e1 * inv;
    u16 h0, l0, h1, l1;
    split2(a0, h0, l0);
    split2(a1, h1, l1);
    Hi[row * NN + t] = h0;
    Hi[row * NN + t + 256] = h1;
    Lo[row * NN + t] = l0;
    Lo[row * NN + t + 256] = l1;
}

// PV: out = elu(att @ Wh), 128x128 tile, depth-2 pipeline.
__global__ __launch_bounds__(256) void k_pv(const u16* __restrict__ Ahi,
                                            const u16* __restrict__ Alo,
                                            const u16* __restrict__ Bhi,
                                            const u16* __restrict__ Blo,
                                            float* __restrict__ OUT) {
    __shared__ __align__(16) u16 lds[2][4][4096];
    const int tid = threadIdx.x;
    const int l = tid & 63, w = tid >> 6;
    const int wr = w >> 1, wc = w & 1;
    const int bz = blockIdx.z;
    const int bm = blockIdx.y * 128, bn = 0;

    const u16* A0p = Ahi + (size_t)bz * NN * NN;
    const u16* A1p = Alo + (size_t)bz * NN * NN;
    const u16* B0p = Bhi + (size_t)bz * FF * NN;
    const u16* B1p = Blo + (size_t)bz * FF * NN;

    const int g0 = w, g1 = w + 4;
    const size_t offA0 = (size_t)(bm + g0 * 16 + (l & 15)) * NN + (l >> 4) * 8;
    const size_t offA1 = (size_t)(bm + g1 * 16 + (l & 15)) * NN + (l >> 4) * 8;
    const size_t offB0 = (size_t)(bn + g0 * 16 + (l & 15)) * NN + (l >> 4) * 8;
    const size_t offB1 = (size_t)(bn + g1 * 16 + (l & 15)) * NN + (l >> 4) * 8;

    auto STAGE = [&](int buf, int kk) {
        gload16(A0p + offA0 + kk, &lds[buf][0][g0 * 512]);
        gload16(A0p + offA1 + kk, &lds[buf][0][g1 * 512]);
        gload16(A1p + offA0 + kk, &lds[buf][1][g0 * 512]);
        gload16(A1p + offA1 + kk, &lds[buf][1][g1 * 512]);
        gload16(B0p + offB0 + kk, &lds[buf][2][g0 * 512]);
        gload16(B0p + offB1 + kk, &lds[buf][2][g1 * 512]);
        gload16(B1p + offB0 + kk, &lds[buf][3][g0 * 512]);
        gload16(B1p + offB1 + kk, &lds[buf][3][g1 * 512]);
    };

    f32x4 acc[4][4];
#pragma unroll
    for (int m = 0; m < 4; ++m)
#pragma unroll
        for (int n = 0; n < 4; ++n) acc[m][n] = (f32x4){0.f, 0.f, 0.f, 0.f};

    STAGE(0, 0);
    for (int t = 0; t < 16; ++t) {
        const int cur = t & 1;
        if (t + 1 < 16) {
            STAGE(cur ^ 1, (t + 1) * 32);
            asm volatile("s_waitcnt vmcnt(8)" ::: "memory");
        } else {
            asm volatile("s_waitcnt vmcnt(0)" ::: "memory");
        }
        __builtin_amdgcn_s_barrier();
        __builtin_amdgcn_sched_barrier(0);
        half8 ah[4], al[4], bh[4], bl[4];
#pragma unroll
        for (int m = 0; m < 4; ++m) {
            ah[m] = *(const half8*)&lds[cur][0][((wr * 4 + m) * 64 + l) * 8];
            al[m] = *(const half8*)&lds[cur][1][((wr * 4 + m) * 64 + l) * 8];
        }
#pragma unroll
        for (int n = 0; n < 4; ++n) {
            bh[n] = *(const half8*)&lds[cur][2][((wc * 4 + n) * 64 + l) * 8];
            bl[n] = *(const half8*)&lds[cur][3][((wc * 4 + n) * 64 + l) * 8];
        }
#pragma unroll
        for (int m = 0; m < 4; ++m) {
#pragma unroll
            for (int n = 0; n < 4; ++n)
                acc[m][n] = __builtin_amdgcn_mfma_f32_16x16x32_f16(ah[m], bh[n], acc[m][n], 0, 0, 0);
        }
#pragma unroll
        for (int m = 0; m < 4; ++m) {
#pragma unroll
            for (int n = 0; n < 4; ++n) {
                acc[m][n] = __builtin_amdgcn_mfma_f32_16x16x32_f16(al[m], bh[n], acc[m][n], 0, 0, 0);
                acc[m][n] = __builtin_amdgcn_mfma_f32_16x16x32_f16(ah[m], bl[n], acc[m][n], 0, 0, 0);
            }
        }
        __builtin_amdgcn_s_barrier();
    }

    const int lr = (l >> 4) * 4, lc = l & 15;
#pragma unroll
    for (int m = 0; m < 4; ++m) {
#pragma unroll
        for (int n = 0; n < 4; ++n) {
#pragma unroll
            for (int j = 0; j < 4; ++j) {
                const int row = bm + wr * 64 + m * 16 + lr + j;
                const int col = bn + wc * 64 + n * 16 + lc;
                const float v = acc[m][n][j];
                OUT[(size_t)bz * NN * FF + (size_t)row * FF + col] =
                    v > 0.f ? v : __expf(v) - 1.f;
            }
        }
    }
}

extern "C" void kernel_launch(void* const* d_in, const int* in_sizes, int n_in,
                              void* d_out, int out_size, void* d_ws, size_t ws_size,
                              hipStream_t stream) {
    const float* h = (const float*)d_in[0];
    const float* W = (const float*)d_in[1];
    const float* a = (const float*)d_in[2];
    const float* A0 = (const float*)d_in[3];
    const float* A2 = (const float*)d_in[4];
    float* out = (float*)d_out;

    char* ws = (char*)d_ws;
    size_t ofs = 0;
    auto alloc = [&](size_t bytes) -> void* {
        void* p = ws + ofs;
        ofs = (ofs + bytes + 255) & ~(size_t)255;
        return p;
    };
    float* u12 = (float*)alloc(2 * FF * sizeof(float));
    float* Wh12 = (float*)alloc(2 * (size_t)BB * NN * sizeof(float));
    u16* WhThi = (u16*)alloc((size_t)BB * FF * NN * 2);
    u16* WhTlo = (u16*)alloc((size_t)BB * FF * NN * 2);
    u16* A0hi = (u16*)alloc((size_t)K4 * NN * 2);
    u16* A0lo = (u16*)alloc((size_t)K4 * NN * 2);
    u16* A2hi = (u16*)alloc((size_t)NN * K4 * 2);
    u16* A2lo = (u16*)alloc((size_t)NN * K4 * 2);

    // per-batch chunk bytes: S hi/lo + fp32 PADJ x2 (Att aliases dead S)
    const size_t per_b = (size_t)NN * K4 * 2 * 2 + (size_t)NN * NN * 4 * 2;
    int cb = BB;
    while (cb > 1 && ofs + (size_t)cb * per_b + 8192 > ws_size) cb >>= 1;
    u16* Shi = (u16*)alloc((size_t)cb * NN * K4 * 2);
    u16* Slo = (u16*)alloc((size_t)cb * NN * K4 * 2);
    float* PADJ = (float*)alloc((size_t)2 * cb * NN * NN * 4);
    u16* AttHi = Shi;  // alias: S dead after g2
    u16* AttLo = Slo;

    k_u<<<1, 128, 0, stream>>>(W, a, u12);
    k_wh12<<<BB * NN, 128, 0, stream>>>(h, u12, Wh12);
    k_whT<<<dim3((BB * NN) / 64, FF / 64), 256, 0, stream>>>(W, h, WhThi, WhTlo);
    k_split<<<(K4 * NN / 4 + 255) / 256, 256, 0, stream>>>(A0, A0hi, A0lo, K4 * NN / 4);
    k_split<<<(NN * K4 / 4 + 255) / 256, 256, 0, stream>>>(A2, A2hi, A2lo, NN * K4 / 4);

    for (int c0 = 0; c0 < BB; c0 += cb) {
        const int c = (BB - c0) < cb ? (BB - c0) : cb;
        const long sK = (long)c * NN * NN;
        const int mb1 = c * 4;   // g1: M = c*512, BM = 128 -> grid mb1 * 8
        // S = sigmoid(E @ A0^T), E on the fly, single-buffered high-occupancy
        k_g1<<<mb1 * (K4 / 256), 512, 0, stream>>>(Wh12, c0, A0hi, A0lo, Shi, Slo, mb1);
        // PADJ[ks] = S @ A2^T partials (K-split x2, single-buffered, c*32 blocks)
        k_g2<<<c * 32, 256, 0, stream>>>(Shi, Slo, A2hi, A2lo, PADJ, sK);
        // combine partials + e + mask + softmax -> att fp16 hi/lo
        k_softmax2<<<c * NN, 256, 0, stream>>>(PADJ, sK, Wh12, c0, AttHi, AttLo);
        // out = elu(att @ Wh)
        k_pv<<<dim3(1, NN / 128, c), 256, 0, stream>>>(
            AttHi, AttLo, WhThi + (size_t)c0 * FF * NN, WhTlo + (size_t)c0 * FF * NN,
            out + (size_t)c0 * NN * FF);
    }
}

// Round 13
// 305.563 us; speedup vs baseline: 1.0354x; 1.0354x over previous
//
#include <hip/hip_runtime.h>

#define BB 32
#define NN 512
#define FF 128
#define K4 2048
#define ALPHA 0.2f
#define THRESH 0.6f
#define NEGINF -9e15f

typedef unsigned short u16;
typedef unsigned int u32;
typedef _Float16 f16;
typedef __attribute__((ext_vector_type(8))) _Float16 half8;
typedef __attribute__((ext_vector_type(4))) float f32x4;

union U16F { u16 u; f16 h; };
__device__ __forceinline__ u16 hbits(f16 h) { U16F x; x.h = h; return x.u; }
__device__ __forceinline__ float htof(u16 u) { U16F x; x.u = u; return (float)x.h; }
__device__ __forceinline__ void split2(float v, u16& hi, u16& lo) {
    f16 h = (f16)v;
    f16 l = (f16)(v - (float)h);
    hi = hbits(h);
    lo = hbits(l);
}
__device__ __forceinline__ float lrelu(float x) { return fmaxf(x, ALPHA * x); }

__device__ __forceinline__ void gload16(const void* g, void* l) {
    __builtin_amdgcn_global_load_lds(
        (__attribute__((address_space(1))) const unsigned int*)(unsigned long long)g,
        (__attribute__((address_space(3))) unsigned int*)(unsigned int)(unsigned long long)l,
        16, 0, 0);
}

// u1[f] = sum_g W[g,f]*a[g];  u2[f] = sum_g W[g,f]*a[F+g]
__global__ void k_u(const float* __restrict__ W, const float* __restrict__ a,
                    float* __restrict__ u12) {
    int f = threadIdx.x;
    float s1 = 0.f, s2 = 0.f;
    for (int g = 0; g < FF; ++g) {
        float w = W[g * FF + f];
        s1 += w * a[g];
        s2 += w * a[FF + g];
    }
    u12[f] = s1;
    u12[FF + f] = s2;
}

// Wh1[row] = h[row,:]·u1 ; Wh2[row] = h[row,:]·u2   (flat row = b*N+n)
__global__ void k_wh12(const float* __restrict__ h, const float* __restrict__ u12,
                       float* __restrict__ Wh12) {
    int row = blockIdx.x;
    int f = threadIdx.x;  // 128
    float hv = h[(size_t)row * FF + f];
    float p1 = hv * u12[f], p2 = hv * u12[FF + f];
#pragma unroll
    for (int o = 1; o < 64; o <<= 1) {
        p1 += __shfl_xor(p1, o, 64);
        p2 += __shfl_xor(p2, o, 64);
    }
    __shared__ float s1[2], s2[2];
    int w = f >> 6;
    if ((f & 63) == 0) { s1[w] = p1; s2[w] = p2; }
    __syncthreads();
    if (f == 0) {
        Wh12[row] = s1[0] + s1[1];
        Wh12[BB * NN + row] = s2[0] + s2[1];
    }
}

// WhT[b][f][n] = (h@W^T)[b][n][f] split into fp16 hi/lo (PV's B operand).
__global__ __launch_bounds__(256) void k_whT(const float* __restrict__ W,
                                             const float* __restrict__ h,
                                             u16* __restrict__ Thi, u16* __restrict__ Tlo) {
    const int bm = blockIdx.y * 64, bn = blockIdx.x * 64;
    __shared__ float As[32][68];
    __shared__ float Bs[32][68];
    int tid = threadIdx.x;
    int tx = tid & 15, ty = tid >> 4;
    float acc[4][4] = {{0.f}};
    int r = tid >> 3, q = tid & 7;
    const float* Ap = W + (size_t)(bm + r) * FF + q * 4;
    const float* Bp = h + (size_t)(bn + r) * FF + q * 4;
    for (int k0 = 0; k0 < FF; k0 += 32) {
        float4 a0 = *(const float4*)(Ap + k0);
        float4 a1 = *(const float4*)(Ap + k0 + 32 * FF);
        float4 b0 = *(const float4*)(Bp + k0);
        float4 b1 = *(const float4*)(Bp + k0 + 32 * FF);
        __syncthreads();
        As[q * 4 + 0][r] = a0.x; As[q * 4 + 1][r] = a0.y;
        As[q * 4 + 2][r] = a0.z; As[q * 4 + 3][r] = a0.w;
        As[q * 4 + 0][r + 32] = a1.x; As[q * 4 + 1][r + 32] = a1.y;
        As[q * 4 + 2][r + 32] = a1.z; As[q * 4 + 3][r + 32] = a1.w;
        Bs[q * 4 + 0][r] = b0.x; Bs[q * 4 + 1][r] = b0.y;
        Bs[q * 4 + 2][r] = b0.z; Bs[q * 4 + 3][r] = b0.w;
        Bs[q * 4 + 0][r + 32] = b1.x; Bs[q * 4 + 1][r + 32] = b1.y;
        Bs[q * 4 + 2][r + 32] = b1.z; Bs[q * 4 + 3][r + 32] = b1.w;
        __syncthreads();
#pragma unroll
        for (int kk = 0; kk < 32; ++kk) {
            float av[4], bv[4];
            *(float4*)av = *(const float4*)&As[kk][ty * 4];
            *(float4*)bv = *(const float4*)&Bs[kk][tx * 4];
#pragma unroll
            for (int i = 0; i < 4; ++i)
#pragma unroll
                for (int j = 0; j < 4; ++j) acc[i][j] = fmaf(av[i], bv[j], acc[i][j]);
        }
    }
#pragma unroll
    for (int i = 0; i < 4; ++i) {
        int f = bm + ty * 4 + i;
#pragma unroll
        for (int j = 0; j < 4; ++j) {
            int mg = bn + tx * 4 + j;
            u16 hi, lo;
            split2(acc[i][j], hi, lo);
            size_t idx = ((size_t)(mg >> 9) * FF + f) * NN + (mg & 511);
            Thi[idx] = hi;
            Tlo[idx] = lo;
        }
    }
}

// fp32 -> fp16 hi/lo split, vectorized
__global__ void k_split(const float* __restrict__ X, u16* __restrict__ Hi,
                        u16* __restrict__ Lo, int n4) {
    int i = blockIdx.x * 256 + threadIdx.x;
    if (i >= n4) return;
    float4 v = *(const float4*)(X + (size_t)i * 4);
    ushort4 hh, ll;
    split2(v.x, hh.x, ll.x);
    split2(v.y, hh.y, ll.y);
    split2(v.z, hh.z, ll.z);
    split2(v.w, hh.w, ll.w);
    *(ushort4*)(Hi + (size_t)i * 4) = hh;
    *(ushort4*)(Lo + (size_t)i * 4) = ll;
}

// GEMM1: S = sigmoid(E @ A0^T), E generated on the fly from Wh12.
// Tile 128x256 (MxN), BK=32, 512 threads (8 waves: 2m x 4n), SINGLE-buffered
// 48KB LDS -> 3 blocks/CU capacity; grid 32*c -> 2 resident blocks/CU.
__global__ __launch_bounds__(512) void k_g1(const float* __restrict__ Wh12, int c0,
                                            const u16* __restrict__ Bhi,
                                            const u16* __restrict__ Blo,
                                            u16* __restrict__ Shi, u16* __restrict__ Slo,
                                            int mblocks) {
    __shared__ __align__(16) u16 ldsA[8192];   // hi [0..4095], lo [4096..8191]
    __shared__ __align__(16) u16 ldsB[16384];  // hi [0..8191], lo [8192..16383]
    __shared__ float wh1s[128];
    __shared__ float wh2s[512];
    const int tid = threadIdx.x;
    const int l = tid & 63, w = tid >> 6;
    const int wm = w >> 2, wn = w & 3;
    const int nwg = gridDim.x, q = nwg >> 3;
    const int wg = (blockIdx.x & 7) * q + (blockIdx.x >> 3);
    const int nb = wg / mblocks, mb = wg % mblocks;
    const int bm = mb * 128, bn = nb * 256;
    const int bglob = c0 + (bm >> 9);

    if (tid < 128) wh1s[tid] = Wh12[(size_t)c0 * NN + bm + tid];
    if (tid < 512) wh2s[tid] = Wh12[BB * NN + (size_t)bglob * NN + tid];

    f32x4 acc[4][4];
#pragma unroll
    for (int m = 0; m < 4; ++m)
#pragma unroll
        for (int n = 0; n < 4; ++n) acc[m][n] = (f32x4){0.f, 0.f, 0.f, 0.f};

    const int gb0 = w * 2, gb1 = w * 2 + 1;
    const size_t rb0 = (size_t)(bn + gb0 * 16 + (l & 15)) * NN + ((l >> 4) * 8);
    const size_t rb1 = (size_t)(bn + gb1 * 16 + (l & 15)) * NN + ((l >> 4) * 8);
    const int arow = (tid >> 6) * 16 + (l & 15);
    const int akc = (l >> 4) * 8;

    __syncthreads();  // wh arrays ready

    const float myw1 = wh1s[arow];

    for (int t = 0; t < 16; ++t) {
        const int k0 = t * 32;
        gload16(Bhi + rb0 + k0, &ldsB[gb0 * 512]);
        gload16(Bhi + rb1 + k0, &ldsB[gb1 * 512]);
        gload16(Blo + rb0 + k0, &ldsB[8192 + gb0 * 512]);
        gload16(Blo + rb1 + k0, &ldsB[8192 + gb1 * 512]);
        {
            const int kc = k0 + akc;
            float w2v[8];
            *(float4*)&w2v[0] = *(const float4*)&wh2s[kc];
            *(float4*)&w2v[4] = *(const float4*)&wh2s[kc + 4];
            u32 hh[4], llv[4];
#pragma unroll
            for (int jj = 0; jj < 4; ++jj) {
                float e0 = lrelu(myw1 + w2v[2 * jj]);
                float e1 = lrelu(myw1 + w2v[2 * jj + 1]);
                u16 h0, l0, h1, l1;
                split2(e0, h0, l0);
                split2(e1, h1, l1);
                hh[jj] = (u32)h0 | ((u32)h1 << 16);
                llv[jj] = (u32)l0 | ((u32)l1 << 16);
            }
            *(uint4*)&ldsA[tid * 8] = make_uint4(hh[0], hh[1], hh[2], hh[3]);
            *(uint4*)&ldsA[4096 + tid * 8] = make_uint4(llv[0], llv[1], llv[2], llv[3]);
        }
        __syncthreads();
        half8 bh[4], bl[4];
#pragma unroll
        for (int n = 0; n < 4; ++n) {
            const int gB = wn * 4 + n;
            bh[n] = *(const half8*)&ldsB[(gB * 64 + l) * 8];
            bl[n] = *(const half8*)&ldsB[8192 + (gB * 64 + l) * 8];
        }
#pragma unroll
        for (int m = 0; m < 4; ++m) {
            const int gA = wm * 4 + m;
            half8 ah = *(const half8*)&ldsA[(gA * 64 + l) * 8];
            half8 al = *(const half8*)&ldsA[4096 + (gA * 64 + l) * 8];
#pragma unroll
            for (int n = 0; n < 4; ++n)
                acc[m][n] = __builtin_amdgcn_mfma_f32_16x16x32_f16(ah, bh[n], acc[m][n], 0, 0, 0);
#pragma unroll
            for (int n = 0; n < 4; ++n)
                acc[m][n] = __builtin_amdgcn_mfma_f32_16x16x32_f16(al, bh[n], acc[m][n], 0, 0, 0);
#pragma unroll
            for (int n = 0; n < 4; ++n)
                acc[m][n] = __builtin_amdgcn_mfma_f32_16x16x32_f16(ah, bl[n], acc[m][n], 0, 0, 0);
        }
        __syncthreads();
    }

    const int lr = (l >> 4) * 4, lc = l & 15;
#pragma unroll
    for (int m = 0; m < 4; ++m) {
#pragma unroll
        for (int n = 0; n < 4; ++n) {
#pragma unroll
            for (int j = 0; j < 4; ++j) {
                const int row = bm + wm * 64 + m * 16 + lr + j;
                const int col = bn + wn * 64 + n * 16 + lc;
                const float s = 1.f / (1.f + __expf(-acc[m][n][j]));
                u16 hi, lo;
                split2(s, hi, lo);
                const size_t idx = (size_t)row * K4 + col;
                Shi[idx] = hi;
                Slo[idx] = lo;
            }
        }
    }
}

// GEMM2: adj = S @ A2^T + e; mask -> packed ADJ (u32: lo<<16|hi of e, or ~0).
// Tile 128x128 (MxN), 512 threads / 8 waves (2m x 4n), wave-tile 64x32,
// TRIPLE-buffered 96KB LDS, depth-3 counted vmcnt(8): each staging load gets
// ~2 K-steps of cover (>900cy HBM latency of the S stream, which is 67MB and
// not L2-resident — the diagnosed g2 limiter).
// Grid = c*4 m-blocks x 4 n-blocks (nb-inner) = 256 blocks at c=16.
__global__ __launch_bounds__(512) void k_g2(const u16* __restrict__ Ahi,
                                            const u16* __restrict__ Alo,
                                            const u16* __restrict__ Bhi,
                                            const u16* __restrict__ Blo,
                                            const float* __restrict__ Wh12, int c0,
                                            u32* __restrict__ ADJ) {
    __shared__ __align__(16) u16 ldsA[3][2][4096];  // [buf][hi/lo][128x32]
    __shared__ __align__(16) u16 ldsB[3][2][4096];
    const int tid = threadIdx.x;
    const int l = tid & 63, w = tid >> 6;  // 8 waves
    const int wm = w >> 2, wn = w & 3;
    const int nwg = gridDim.x, q = nwg >> 3;
    const int wg = ((int)blockIdx.x & 7) * q + ((int)blockIdx.x >> 3);
    const int mb = wg >> 2, nb = wg & 3;  // nb-inner: same-A blocks adjacent
    const int bm = mb * 128, bn = nb * 128;

    // staging: wave w owns row-group w (16 rows) of A and of B: 4 loads/wave
    const size_t ra = (size_t)(bm + w * 16 + (l & 15)) * K4 + ((l >> 4) * 8);
    const size_t rb = (size_t)(bn + w * 16 + (l & 15)) * K4 + ((l >> 4) * 8);

    auto STAGE = [&](int buf, int k0) {
        gload16(Ahi + ra + k0, &ldsA[buf][0][w * 512]);
        gload16(Alo + ra + k0, &ldsA[buf][1][w * 512]);
        gload16(Bhi + rb + k0, &ldsB[buf][0][w * 512]);
        gload16(Blo + rb + k0, &ldsB[buf][1][w * 512]);
    };

    f32x4 acc[4][2];
#pragma unroll
    for (int m = 0; m < 4; ++m)
#pragma unroll
        for (int n = 0; n < 2; ++n) acc[m][n] = (f32x4){0.f, 0.f, 0.f, 0.f};

    // prologue: two tiles in flight
    STAGE(0, 0);
    STAGE(1, 32);
    for (int t = 0; t < 64; ++t) {
        const int cur = t % 3;
        if (t < 62) {
            STAGE((t + 2) % 3, (t + 2) * 32);
            // outstanding/wave after issue: t+1 (4) + t+2 (4) = 8 -> t's landed
            asm volatile("s_waitcnt vmcnt(8)" ::: "memory");
        } else if (t == 62) {
            asm volatile("s_waitcnt vmcnt(4)" ::: "memory");
        } else {
            asm volatile("s_waitcnt vmcnt(0)" ::: "memory");
        }
        __builtin_amdgcn_s_barrier();
        __builtin_amdgcn_sched_barrier(0);
        half8 bh[2], bl[2];
#pragma unroll
        for (int n = 0; n < 2; ++n) {
            const int gB = wn * 2 + n;
            bh[n] = *(const half8*)&ldsB[cur][0][(gB * 64 + l) * 8];
            bl[n] = *(const half8*)&ldsB[cur][1][(gB * 64 + l) * 8];
        }
        __builtin_amdgcn_s_setprio(1);
#pragma unroll
        for (int m = 0; m < 4; ++m) {
            const int gA = wm * 4 + m;
            half8 ah = *(const half8*)&ldsA[cur][0][(gA * 64 + l) * 8];
            half8 al = *(const half8*)&ldsA[cur][1][(gA * 64 + l) * 8];
#pragma unroll
            for (int n = 0; n < 2; ++n)
                acc[m][n] = __builtin_amdgcn_mfma_f32_16x16x32_f16(ah, bh[n], acc[m][n], 0, 0, 0);
#pragma unroll
            for (int n = 0; n < 2; ++n)
                acc[m][n] = __builtin_amdgcn_mfma_f32_16x16x32_f16(al, bh[n], acc[m][n], 0, 0, 0);
#pragma unroll
            for (int n = 0; n < 2; ++n)
                acc[m][n] = __builtin_amdgcn_mfma_f32_16x16x32_f16(ah, bl[n], acc[m][n], 0, 0, 0);
        }
        __builtin_amdgcn_s_setprio(0);
        __builtin_amdgcn_sched_barrier(0);
        __builtin_amdgcn_s_barrier();
    }

    const int bglob = c0 + (bm >> 9);
    const float* wh2p = Wh12 + BB * NN + (size_t)bglob * NN;
    const int lr = (l >> 4) * 4, lc = l & 15;
#pragma unroll
    for (int m = 0; m < 4; ++m) {
#pragma unroll
        for (int n = 0; n < 2; ++n) {
#pragma unroll
            for (int j = 0; j < 4; ++j) {
                const int row = bm + wm * 64 + m * 16 + lr + j;
                const int col = bn + wn * 32 + n * 16 + lc;
                const float e = lrelu(Wh12[(size_t)c0 * NN + row] + wh2p[col]);
                u32 pk = 0xFFFFFFFFu;
                if (e + acc[m][n][j] > THRESH) {
                    u16 hi, lo;
                    split2(e, hi, lo);
                    pk = (u32)hi | ((u32)lo << 16);
                }
                ADJ[(size_t)row * NN + col] = pk;
            }
        }
    }
}

// softmax rows of packed ADJ, write att as fp16 hi/lo
__global__ __launch_bounds__(256) void k_softmax2(const u32* __restrict__ ADJ,
                                                  u16* __restrict__ Hi, u16* __restrict__ Lo) {
    const size_t row = blockIdx.x;
    const u32* p = ADJ + row * NN;
    const int t = threadIdx.x;
    u32 w0 = p[t], w1 = p[t + 256];
    float v0 = (w0 == 0xFFFFFFFFu) ? NEGINF : htof((u16)(w0 & 0xFFFF)) + htof((u16)(w0 >> 16));
    float v1 = (w1 == 0xFFFFFFFFu) ? NEGINF : htof((u16)(w1 & 0xFFFF)) + htof((u16)(w1 >> 16));
    float m = fmaxf(v0, v1);
#pragma unroll
    for (int o = 1; o < 64; o <<= 1) m = fmaxf(m, __shfl_xor(m, o, 64));
    __shared__ float red[4], red2[4];
    int w = t >> 6;
    if ((t & 63) == 0) red[w] = m;
    __syncthreads();
    m = fmaxf(fmaxf(red[0], red[1]), fmaxf(red[2], red[3]));
    float e0 = __expf(v0 - m), e1 = __expf(v1 - m);
    float s = e0 + e1;
#pragma unroll
    for (int o = 1; o < 64; o <<= 1) s += __shfl_xor(s, o, 64);
    if ((t & 63) == 0) red2[w] = s;
    __syncthreads();
    s = red2[0] + red2[1] + red2[2] + red2[3];
    float inv = 1.f / s;
    float a0 = e0 * inv, a1 = e1 * inv;
    u16 h0, l0, h1, l1;
    split2(a0, h0, l0);
    split2(a1, h1, l1);
    Hi[row * NN + t] = h0;
    Hi[row * NN + t + 256] = h1;
    Lo[row * NN + t] = l0;
    Lo[row * NN + t + 256] = l1;
}

// PV: out = elu(att @ Wh), 128x128 tile, depth-2 pipeline.
__global__ __launch_bounds__(256) void k_pv(const u16* __restrict__ Ahi,
                                            const u16* __restrict__ Alo,
                                            const u16* __restrict__ Bhi,
                                            const u16* __restrict__ Blo,
                                            float* __restrict__ OUT) {
    __shared__ __align__(16) u16 lds[2][4][4096];
    const int tid = threadIdx.x;
    const int l = tid & 63, w = tid >> 6;
    const int wr = w >> 1, wc = w & 1;
    const int bz = blockIdx.z;
    const int bm = blockIdx.y * 128, bn = 0;

    const u16* A0p = Ahi + (size_t)bz * NN * NN;
    const u16* A1p = Alo + (size_t)bz * NN * NN;
    const u16* B0p = Bhi + (size_t)bz * FF * NN;
    const u16* B1p = Blo + (size_t)bz * FF * NN;

    const int g0 = w, g1 = w + 4;
    const size_t offA0 = (size_t)(bm + g0 * 16 + (l & 15)) * NN + (l >> 4) * 8;
    const size_t offA1 = (size_t)(bm + g1 * 16 + (l & 15)) * NN + (l >> 4) * 8;
    const size_t offB0 = (size_t)(bn + g0 * 16 + (l & 15)) * NN + (l >> 4) * 8;
    const size_t offB1 = (size_t)(bn + g1 * 16 + (l & 15)) * NN + (l >> 4) * 8;

    auto STAGE = [&](int buf, int kk) {
        gload16(A0p + offA0 + kk, &lds[buf][0][g0 * 512]);
        gload16(A0p + offA1 + kk, &lds[buf][0][g1 * 512]);
        gload16(A1p + offA0 + kk, &lds[buf][1][g0 * 512]);
        gload16(A1p + offA1 + kk, &lds[buf][1][g1 * 512]);
        gload16(B0p + offB0 + kk, &lds[buf][2][g0 * 512]);
        gload16(B0p + offB1 + kk, &lds[buf][2][g1 * 512]);
        gload16(B1p + offB0 + kk, &lds[buf][3][g0 * 512]);
        gload16(B1p + offB1 + kk, &lds[buf][3][g1 * 512]);
    };

    f32x4 acc[4][4];
#pragma unroll
    for (int m = 0; m < 4; ++m)
#pragma unroll
        for (int n = 0; n < 4; ++n) acc[m][n] = (f32x4){0.f, 0.f, 0.f, 0.f};

    STAGE(0, 0);
    for (int t = 0; t < 16; ++t) {
        const int cur = t & 1;
        if (t + 1 < 16) {
            STAGE(cur ^ 1, (t + 1) * 32);
            asm volatile("s_waitcnt vmcnt(8)" ::: "memory");
        } else {
            asm volatile("s_waitcnt vmcnt(0)" ::: "memory");
        }
        __builtin_amdgcn_s_barrier();
        __builtin_amdgcn_sched_barrier(0);
        half8 ah[4], al[4], bh[4], bl[4];
#pragma unroll
        for (int m = 0; m < 4; ++m) {
            ah[m] = *(const half8*)&lds[cur][0][((wr * 4 + m) * 64 + l) * 8];
            al[m] = *(const half8*)&lds[cur][1][((wr * 4 + m) * 64 + l) * 8];
        }
#pragma unroll
        for (int n = 0; n < 4; ++n) {
            bh[n] = *(const half8*)&lds[cur][2][((wc * 4 + n) * 64 + l) * 8];
            bl[n] = *(const half8*)&lds[cur][3][((wc * 4 + n) * 64 + l) * 8];
        }
#pragma unroll
        for (int m = 0; m < 4; ++m) {
#pragma unroll
            for (int n = 0; n < 4; ++n)
                acc[m][n] = __builtin_amdgcn_mfma_f32_16x16x32_f16(ah[m], bh[n], acc[m][n], 0, 0, 0);
        }
#pragma unroll
        for (int m = 0; m < 4; ++m) {
#pragma unroll
            for (int n = 0; n < 4; ++n) {
                acc[m][n] = __builtin_amdgcn_mfma_f32_16x16x32_f16(al[m], bh[n], acc[m][n], 0, 0, 0);
                acc[m][n] = __builtin_amdgcn_mfma_f32_16x16x32_f16(ah[m], bl[n], acc[m][n], 0, 0, 0);
            }
        }
        __builtin_amdgcn_s_barrier();
    }

    const int lr = (l >> 4) * 4, lc = l & 15;
#pragma unroll
    for (int m = 0; m < 4; ++m) {
#pragma unroll
        for (int n = 0; n < 4; ++n) {
#pragma unroll
            for (int j = 0; j < 4; ++j) {
                const int row = bm + wr * 64 + m * 16 + lr + j;
                const int col = bn + wc * 64 + n * 16 + lc;
                const float v = acc[m][n][j];
                OUT[(size_t)bz * NN * FF + (size_t)row * FF + col] =
                    v > 0.f ? v : __expf(v) - 1.f;
            }
        }
    }
}

extern "C" void kernel_launch(void* const* d_in, const int* in_sizes, int n_in,
                              void* d_out, int out_size, void* d_ws, size_t ws_size,
                              hipStream_t stream) {
    const float* h = (const float*)d_in[0];
    const float* W = (const float*)d_in[1];
    const float* a = (const float*)d_in[2];
    const float* A0 = (const float*)d_in[3];
    const float* A2 = (const float*)d_in[4];
    float* out = (float*)d_out;

    char* ws = (char*)d_ws;
    size_t ofs = 0;
    auto alloc = [&](size_t bytes) -> void* {
        void* p = ws + ofs;
        ofs = (ofs + bytes + 255) & ~(size_t)255;
        return p;
    };
    float* u12 = (float*)alloc(2 * FF * sizeof(float));
    float* Wh12 = (float*)alloc(2 * (size_t)BB * NN * sizeof(float));
    u16* WhThi = (u16*)alloc((size_t)BB * FF * NN * 2);
    u16* WhTlo = (u16*)alloc((size_t)BB * FF * NN * 2);
    u16* A0hi = (u16*)alloc((size_t)K4 * NN * 2);
    u16* A0lo = (u16*)alloc((size_t)K4 * NN * 2);
    u16* A2hi = (u16*)alloc((size_t)NN * K4 * 2);
    u16* A2lo = (u16*)alloc((size_t)NN * K4 * 2);

    // per-batch chunk bytes: S hi/lo + packed ADJ (Att aliases dead S)
    const size_t per_b = (size_t)NN * K4 * 2 * 2 + (size_t)NN * NN * 4;
    int cb = BB;
    while (cb > 1 && ofs + (size_t)cb * per_b + 8192 > ws_size) cb >>= 1;
    u16* Shi = (u16*)alloc((size_t)cb * NN * K4 * 2);
    u16* Slo = (u16*)alloc((size_t)cb * NN * K4 * 2);
    u32* ADJ = (u32*)alloc((size_t)cb * NN * NN * 4);
    u16* AttHi = Shi;  // alias: S dead after g2
    u16* AttLo = Slo;

    k_u<<<1, 128, 0, stream>>>(W, a, u12);
    k_wh12<<<BB * NN, 128, 0, stream>>>(h, u12, Wh12);
    k_whT<<<dim3((BB * NN) / 64, FF / 64), 256, 0, stream>>>(W, h, WhThi, WhTlo);
    k_split<<<(K4 * NN / 4 + 255) / 256, 256, 0, stream>>>(A0, A0hi, A0lo, K4 * NN / 4);
    k_split<<<(NN * K4 / 4 + 255) / 256, 256, 0, stream>>>(A2, A2hi, A2lo, NN * K4 / 4);

    for (int c0 = 0; c0 < BB; c0 += cb) {
        const int c = (BB - c0) < cb ? (BB - c0) : cb;
        const int mb1 = c * 4;   // g1: M = c*512, BM = 128 -> grid mb1 * 8
        // S = sigmoid(E @ A0^T), E on the fly, single-buffered high-occupancy
        k_g1<<<mb1 * (K4 / 256), 512, 0, stream>>>(Wh12, c0, A0hi, A0lo, Shi, Slo, mb1);
        // adj = S @ A2^T + e; mask -> packed ADJ (triple-buffered depth-3)
        k_g2<<<c * 16, 512, 0, stream>>>(Shi, Slo, A2hi, A2lo, Wh12, c0, ADJ);
        k_softmax2<<<c * NN, 256, 0, stream>>>(ADJ, AttHi, AttLo);
        // out = elu(att @ Wh)
        k_pv<<<dim3(1, NN / 128, c), 256, 0, stream>>>(
            AttHi, AttLo, WhThi + (size_t)c0 * FF * NN, WhTlo + (size_t)c0 * FF * NN,
            out + (size_t)c0 * NN * FF);
    }
}

// Round 14
// 275.286 us; speedup vs baseline: 1.1493x; 1.1100x over previous
//
#include <hip/hip_runtime.h>

#define BB 32
#define NN 512
#define FF 128
#define K4 2048
#define ALPHA 0.2f
#define THRESH 0.6f
#define NEGINF -9e15f

typedef unsigned short u16;
typedef unsigned int u32;
typedef _Float16 f16;
typedef __attribute__((ext_vector_type(8))) _Float16 half8;
typedef __attribute__((ext_vector_type(4))) float f32x4;

union U16F { u16 u; f16 h; };
__device__ __forceinline__ u16 hbits(f16 h) { U16F x; x.h = h; return x.u; }
__device__ __forceinline__ float htof(u16 u) { U16F x; x.u = u; return (float)x.h; }
__device__ __forceinline__ void split2(float v, u16& hi, u16& lo) {
    f16 h = (f16)v;
    f16 l = (f16)(v - (float)h);
    hi = hbits(h);
    lo = hbits(l);
}
__device__ __forceinline__ float lrelu(float x) { return fmaxf(x, ALPHA * x); }

__device__ __forceinline__ void gload16(const void* g, void* l) {
    __builtin_amdgcn_global_load_lds(
        (__attribute__((address_space(1))) const unsigned int*)(unsigned long long)g,
        (__attribute__((address_space(3))) unsigned int*)(unsigned int)(unsigned long long)l,
        16, 0, 0);
}

// u1[f] = sum_g W[g,f]*a[g];  u2[f] = sum_g W[g,f]*a[F+g]
__global__ void k_u(const float* __restrict__ W, const float* __restrict__ a,
                    float* __restrict__ u12) {
    int f = threadIdx.x;
    float s1 = 0.f, s2 = 0.f;
    for (int g = 0; g < FF; ++g) {
        float w = W[g * FF + f];
        s1 += w * a[g];
        s2 += w * a[FF + g];
    }
    u12[f] = s1;
    u12[FF + f] = s2;
}

// Wh1[row] = h[row,:]·u1 ; Wh2[row] = h[row,:]·u2   (flat row = b*N+n)
__global__ void k_wh12(const float* __restrict__ h, const float* __restrict__ u12,
                       float* __restrict__ Wh12) {
    int row = blockIdx.x;
    int f = threadIdx.x;  // 128
    float hv = h[(size_t)row * FF + f];
    float p1 = hv * u12[f], p2 = hv * u12[FF + f];
#pragma unroll
    for (int o = 1; o < 64; o <<= 1) {
        p1 += __shfl_xor(p1, o, 64);
        p2 += __shfl_xor(p2, o, 64);
    }
    __shared__ float s1[2], s2[2];
    int w = f >> 6;
    if ((f & 63) == 0) { s1[w] = p1; s2[w] = p2; }
    __syncthreads();
    if (f == 0) {
        Wh12[row] = s1[0] + s1[1];
        Wh12[BB * NN + row] = s2[0] + s2[1];
    }
}

// WhT[b][f][n] = (h@W^T)[b][n][f], fp16 hi only (PV tolerates 2^-11 on Wh).
__global__ __launch_bounds__(256) void k_whT(const float* __restrict__ W,
                                             const float* __restrict__ h,
                                             u16* __restrict__ Thi) {
    const int bm = blockIdx.y * 64, bn = blockIdx.x * 64;
    __shared__ float As[32][68];
    __shared__ float Bs[32][68];
    int tid = threadIdx.x;
    int tx = tid & 15, ty = tid >> 4;
    float acc[4][4] = {{0.f}};
    int r = tid >> 3, q = tid & 7;
    const float* Ap = W + (size_t)(bm + r) * FF + q * 4;
    const float* Bp = h + (size_t)(bn + r) * FF + q * 4;
    for (int k0 = 0; k0 < FF; k0 += 32) {
        float4 a0 = *(const float4*)(Ap + k0);
        float4 a1 = *(const float4*)(Ap + k0 + 32 * FF);
        float4 b0 = *(const float4*)(Bp + k0);
        float4 b1 = *(const float4*)(Bp + k0 + 32 * FF);
        __syncthreads();
        As[q * 4 + 0][r] = a0.x; As[q * 4 + 1][r] = a0.y;
        As[q * 4 + 2][r] = a0.z; As[q * 4 + 3][r] = a0.w;
        As[q * 4 + 0][r + 32] = a1.x; As[q * 4 + 1][r + 32] = a1.y;
        As[q * 4 + 2][r + 32] = a1.z; As[q * 4 + 3][r + 32] = a1.w;
        Bs[q * 4 + 0][r] = b0.x; Bs[q * 4 + 1][r] = b0.y;
        Bs[q * 4 + 2][r] = b0.z; Bs[q * 4 + 3][r] = b0.w;
        Bs[q * 4 + 0][r + 32] = b1.x; Bs[q * 4 + 1][r + 32] = b1.y;
        Bs[q * 4 + 2][r + 32] = b1.z; Bs[q * 4 + 3][r + 32] = b1.w;
        __syncthreads();
#pragma unroll
        for (int kk = 0; kk < 32; ++kk) {
            float av[4], bv[4];
            *(float4*)av = *(const float4*)&As[kk][ty * 4];
            *(float4*)bv = *(const float4*)&Bs[kk][tx * 4];
#pragma unroll
            for (int i = 0; i < 4; ++i)
#pragma unroll
                for (int j = 0; j < 4; ++j) acc[i][j] = fmaf(av[i], bv[j], acc[i][j]);
        }
    }
#pragma unroll
    for (int i = 0; i < 4; ++i) {
        int f = bm + ty * 4 + i;
#pragma unroll
        for (int j = 0; j < 4; ++j) {
            int mg = bn + tx * 4 + j;
            size_t idx = ((size_t)(mg >> 9) * FF + f) * NN + (mg & 511);
            Thi[idx] = hbits((f16)acc[i][j]);
        }
    }
}

// fp32 -> fp16 hi/lo split, vectorized
__global__ void k_split(const float* __restrict__ X, u16* __restrict__ Hi,
                        u16* __restrict__ Lo, int n4) {
    int i = blockIdx.x * 256 + threadIdx.x;
    if (i >= n4) return;
    float4 v = *(const float4*)(X + (size_t)i * 4);
    ushort4 hh, ll;
    split2(v.x, hh.x, ll.x);
    split2(v.y, hh.y, ll.y);
    split2(v.z, hh.z, ll.z);
    split2(v.w, hh.w, ll.w);
    *(ushort4*)(Hi + (size_t)i * 4) = hh;
    *(ushort4*)(Lo + (size_t)i * 4) = ll;
}

// GEMM1: S = sigmoid(E @ A0^T), E generated on the fly from Wh12.
// Tile 128x256 (MxN), BK=32, 512 threads (8 waves: 2m x 4n), SINGLE-buffered
// 48KB LDS -> 3 blocks/CU capacity; grid 32*c -> 2 resident blocks/CU.
__global__ __launch_bounds__(512) void k_g1(const float* __restrict__ Wh12, int c0,
                                            const u16* __restrict__ Bhi,
                                            const u16* __restrict__ Blo,
                                            u16* __restrict__ Shi, u16* __restrict__ Slo,
                                            int mblocks) {
    __shared__ __align__(16) u16 ldsA[8192];   // hi [0..4095], lo [4096..8191]
    __shared__ __align__(16) u16 ldsB[16384];  // hi [0..8191], lo [8192..16383]
    __shared__ float wh1s[128];
    __shared__ float wh2s[512];
    const int tid = threadIdx.x;
    const int l = tid & 63, w = tid >> 6;
    const int wm = w >> 2, wn = w & 3;
    const int nwg = gridDim.x, q = nwg >> 3;
    const int wg = (blockIdx.x & 7) * q + (blockIdx.x >> 3);
    const int nb = wg / mblocks, mb = wg % mblocks;
    const int bm = mb * 128, bn = nb * 256;
    const int bglob = c0 + (bm >> 9);

    if (tid < 128) wh1s[tid] = Wh12[(size_t)c0 * NN + bm + tid];
    if (tid < 512) wh2s[tid] = Wh12[BB * NN + (size_t)bglob * NN + tid];

    f32x4 acc[4][4];
#pragma unroll
    for (int m = 0; m < 4; ++m)
#pragma unroll
        for (int n = 0; n < 4; ++n) acc[m][n] = (f32x4){0.f, 0.f, 0.f, 0.f};

    const int gb0 = w * 2, gb1 = w * 2 + 1;
    const size_t rb0 = (size_t)(bn + gb0 * 16 + (l & 15)) * NN + ((l >> 4) * 8);
    const size_t rb1 = (size_t)(bn + gb1 * 16 + (l & 15)) * NN + ((l >> 4) * 8);
    const int arow = (tid >> 6) * 16 + (l & 15);
    const int akc = (l >> 4) * 8;

    __syncthreads();  // wh arrays ready

    const float myw1 = wh1s[arow];

    for (int t = 0; t < 16; ++t) {
        const int k0 = t * 32;
        gload16(Bhi + rb0 + k0, &ldsB[gb0 * 512]);
        gload16(Bhi + rb1 + k0, &ldsB[gb1 * 512]);
        gload16(Blo + rb0 + k0, &ldsB[8192 + gb0 * 512]);
        gload16(Blo + rb1 + k0, &ldsB[8192 + gb1 * 512]);
        {
            const int kc = k0 + akc;
            float w2v[8];
            *(float4*)&w2v[0] = *(const float4*)&wh2s[kc];
            *(float4*)&w2v[4] = *(const float4*)&wh2s[kc + 4];
            u32 hh[4], llv[4];
#pragma unroll
            for (int jj = 0; jj < 4; ++jj) {
                float e0 = lrelu(myw1 + w2v[2 * jj]);
                float e1 = lrelu(myw1 + w2v[2 * jj + 1]);
                u16 h0, l0, h1, l1;
                split2(e0, h0, l0);
                split2(e1, h1, l1);
                hh[jj] = (u32)h0 | ((u32)h1 << 16);
                llv[jj] = (u32)l0 | ((u32)l1 << 16);
            }
            *(uint4*)&ldsA[tid * 8] = make_uint4(hh[0], hh[1], hh[2], hh[3]);
            *(uint4*)&ldsA[4096 + tid * 8] = make_uint4(llv[0], llv[1], llv[2], llv[3]);
        }
        __syncthreads();
        half8 bh[4], bl[4];
#pragma unroll
        for (int n = 0; n < 4; ++n) {
            const int gB = wn * 4 + n;
            bh[n] = *(const half8*)&ldsB[(gB * 64 + l) * 8];
            bl[n] = *(const half8*)&ldsB[8192 + (gB * 64 + l) * 8];
        }
#pragma unroll
        for (int m = 0; m < 4; ++m) {
            const int gA = wm * 4 + m;
            half8 ah = *(const half8*)&ldsA[(gA * 64 + l) * 8];
            half8 al = *(const half8*)&ldsA[4096 + (gA * 64 + l) * 8];
#pragma unroll
            for (int n = 0; n < 4; ++n)
                acc[m][n] = __builtin_amdgcn_mfma_f32_16x16x32_f16(ah, bh[n], acc[m][n], 0, 0, 0);
#pragma unroll
            for (int n = 0; n < 4; ++n)
                acc[m][n] = __builtin_amdgcn_mfma_f32_16x16x32_f16(al, bh[n], acc[m][n], 0, 0, 0);
#pragma unroll
            for (int n = 0; n < 4; ++n)
                acc[m][n] = __builtin_amdgcn_mfma_f32_16x16x32_f16(ah, bl[n], acc[m][n], 0, 0, 0);
        }
        __syncthreads();
    }

    const int lr = (l >> 4) * 4, lc = l & 15;
#pragma unroll
    for (int m = 0; m < 4; ++m) {
#pragma unroll
        for (int n = 0; n < 4; ++n) {
#pragma unroll
            for (int j = 0; j < 4; ++j) {
                const int row = bm + wm * 64 + m * 16 + lr + j;
                const int col = bn + wn * 64 + n * 16 + lc;
                const float s = 1.f / (1.f + __expf(-acc[m][n][j]));
                u16 hi, lo;
                split2(s, hi, lo);
                const size_t idx = (size_t)row * K4 + col;
                Shi[idx] = hi;
                Slo[idx] = lo;
            }
        }
    }
}

// GEMM2 (r8 exact — empirical argmin): adj = S @ A2^T + e; mask -> packed ADJ.
// Tile 128x256, BK=32, 8 waves, 96 KB LDS, counted vmcnt(6) depth-2.
__global__ __launch_bounds__(512, 2) void k_g2(const u16* __restrict__ Ahi,
                                               const u16* __restrict__ Alo,
                                               const u16* __restrict__ Bhi,
                                               const u16* __restrict__ Blo,
                                               const float* __restrict__ Wh12, int c0,
                                               u32* __restrict__ ADJ, int mblocks) {
    __shared__ __align__(16) u16 ldsA[2][2][4096];
    __shared__ __align__(16) u16 ldsB[2][2][8192];
    const int tid = threadIdx.x;
    const int l = tid & 63, w = tid >> 6;
    const int nwg = gridDim.x, q = nwg >> 3;
    const int wg = ((int)blockIdx.x & 7) * q + ((int)blockIdx.x >> 3);
    const int nb = wg / mblocks, mb = wg % mblocks;
    const int bm = mb * 128, bn = nb * 256;

    auto STAGE = [&](int buf, int k0) {
        const size_t ra = (size_t)(bm + w * 16 + (l & 15)) * K4 + k0 + ((l >> 4) * 8);
        gload16(Ahi + ra, &ldsA[buf][0][w * 512]);
        gload16(Alo + ra, &ldsA[buf][1][w * 512]);
#pragma unroll
        for (int i = 0; i < 2; ++i) {
            const int g = w * 2 + i;
            const size_t rb = (size_t)(bn + g * 16 + (l & 15)) * K4 + k0 + ((l >> 4) * 8);
            gload16(Bhi + rb, &ldsB[buf][0][g * 512]);
            gload16(Blo + rb, &ldsB[buf][1][g * 512]);
        }
    };

    f32x4 acc[4][4];
#pragma unroll
    for (int m = 0; m < 4; ++m)
#pragma unroll
        for (int n = 0; n < 4; ++n) acc[m][n] = (f32x4){0.f, 0.f, 0.f, 0.f};

    STAGE(0, 0);
    for (int t = 0; t < 64; ++t) {
        const int cur = t & 1;
        if (t < 63) {
            STAGE(cur ^ 1, (t + 1) * 32);
            asm volatile("s_waitcnt vmcnt(6)" ::: "memory");
        } else {
            asm volatile("s_waitcnt vmcnt(0)" ::: "memory");
        }
        __builtin_amdgcn_s_barrier();
        __builtin_amdgcn_sched_barrier(0);
        half8 bh[4], bl[4];
#pragma unroll
        for (int n = 0; n < 4; ++n) {
            const int gB = (w & 3) * 4 + n;
            bh[n] = *(const half8*)&ldsB[cur][0][(gB * 64 + l) * 8];
            bl[n] = *(const half8*)&ldsB[cur][1][(gB * 64 + l) * 8];
        }
        __builtin_amdgcn_s_setprio(1);
#pragma unroll
        for (int m = 0; m < 4; ++m) {
            const int gA = (w >> 2) * 4 + m;
            half8 ah = *(const half8*)&ldsA[cur][0][(gA * 64 + l) * 8];
            half8 al = *(const half8*)&ldsA[cur][1][(gA * 64 + l) * 8];
#pragma unroll
            for (int n = 0; n < 4; ++n)
                acc[m][n] = __builtin_amdgcn_mfma_f32_16x16x32_f16(ah, bh[n], acc[m][n], 0, 0, 0);
#pragma unroll
            for (int n = 0; n < 4; ++n)
                acc[m][n] = __builtin_amdgcn_mfma_f32_16x16x32_f16(al, bh[n], acc[m][n], 0, 0, 0);
#pragma unroll
            for (int n = 0; n < 4; ++n)
                acc[m][n] = __builtin_amdgcn_mfma_f32_16x16x32_f16(ah, bl[n], acc[m][n], 0, 0, 0);
        }
        __builtin_amdgcn_s_setprio(0);
        __builtin_amdgcn_sched_barrier(0);
        __builtin_amdgcn_s_barrier();
    }

    const int bglob = c0 + (bm >> 9);
    const float* wh2p = Wh12 + BB * NN + (size_t)bglob * NN;
    const int lr = (l >> 4) * 4, lc = l & 15;
#pragma unroll
    for (int m = 0; m < 4; ++m) {
#pragma unroll
        for (int n = 0; n < 4; ++n) {
#pragma unroll
            for (int j = 0; j < 4; ++j) {
                const int row = bm + (w >> 2) * 64 + m * 16 + lr + j;
                const int col = bn + (w & 3) * 64 + n * 16 + lc;
                const float e = lrelu(Wh12[(size_t)c0 * NN + row] + wh2p[col]);
                u32 pk = 0xFFFFFFFFu;
                if (e + acc[m][n][j] > THRESH) {
                    u16 hi, lo;
                    split2(e, hi, lo);
                    pk = (u32)hi | ((u32)lo << 16);
                }
                ADJ[(size_t)row * NN + col] = pk;
            }
        }
    }
}

// softmax rows of packed ADJ, write att as fp16 hi ONLY (PV error budget).
__global__ __launch_bounds__(256) void k_softmax2(const u32* __restrict__ ADJ,
                                                  u16* __restrict__ Hi) {
    const size_t row = blockIdx.x;
    const u32* p = ADJ + row * NN;
    const int t = threadIdx.x;
    u32 w0 = p[t], w1 = p[t + 256];
    float v0 = (w0 == 0xFFFFFFFFu) ? NEGINF : htof((u16)(w0 & 0xFFFF)) + htof((u16)(w0 >> 16));
    float v1 = (w1 == 0xFFFFFFFFu) ? NEGINF : htof((u16)(w1 & 0xFFFF)) + htof((u16)(w1 >> 16));
    float m = fmaxf(v0, v1);
#pragma unroll
    for (int o = 1; o < 64; o <<= 1) m = fmaxf(m, __shfl_xor(m, o, 64));
    __shared__ float red[4], red2[4];
    int w = t >> 6;
    if ((t & 63) == 0) red[w] = m;
    __syncthreads();
    m = fmaxf(fmaxf(red[0], red[1]), fmaxf(red[2], red[3]));
    float e0 = __expf(v0 - m), e1 = __expf(v1 - m);
    float s = e0 + e1;
#pragma unroll
    for (int o = 1; o < 64; o <<= 1) s += __shfl_xor(s, o, 64);
    if ((t & 63) == 0) red2[w] = s;
    __syncthreads();
    s = red2[0] + red2[1] + red2[2] + red2[3];
    float inv = 1.f / s;
    Hi[row * NN + t] = hbits((f16)(e0 * inv));
    Hi[row * NN + t + 256] = hbits((f16)(e1 * inv));
}

// PV: out = elu(att @ Wh), single-term fp16 (att_hi x Wh_hi).
// BM=64, 256 threads / 4 waves (2m x 2n), wave-tile 32x64, 24KB LDS,
// counted vmcnt(3) depth-2. Grid = 8 x c*... dim3(1, 8, c) = 256 blocks.
__global__ __launch_bounds__(256) void k_pv(const u16* __restrict__ Ahi,
                                            const u16* __restrict__ Bhi,
                                            float* __restrict__ OUT) {
    __shared__ __align__(16) u16 ldsA[2][2048];  // 64x32
    __shared__ __align__(16) u16 ldsB[2][4096];  // 128x32
    const int tid = threadIdx.x;
    const int l = tid & 63, w = tid >> 6;  // 4 waves
    const int wr = w >> 1, wc = w & 1;
    const int bz = blockIdx.z;
    const int bm = blockIdx.y * 64;

    const u16* Ap = Ahi + (size_t)bz * NN * NN;
    const u16* Bp = Bhi + (size_t)bz * FF * NN;

    const size_t offA = (size_t)(bm + w * 16 + (l & 15)) * NN + (l >> 4) * 8;
    const size_t offB0 = (size_t)((w * 2 + 0) * 16 + (l & 15)) * NN + (l >> 4) * 8;
    const size_t offB1 = (size_t)((w * 2 + 1) * 16 + (l & 15)) * NN + (l >> 4) * 8;

    auto STAGE = [&](int buf, int kk) {
        gload16(Ap + offA + kk, &ldsA[buf][w * 512]);
        gload16(Bp + offB0 + kk, &ldsB[buf][(w * 2 + 0) * 512]);
        gload16(Bp + offB1 + kk, &ldsB[buf][(w * 2 + 1) * 512]);
    };

    f32x4 acc[2][4];
#pragma unroll
    for (int m = 0; m < 2; ++m)
#pragma unroll
        for (int n = 0; n < 4; ++n) acc[m][n] = (f32x4){0.f, 0.f, 0.f, 0.f};

    STAGE(0, 0);
    for (int t = 0; t < 16; ++t) {
        const int cur = t & 1;
        if (t + 1 < 16) {
            STAGE(cur ^ 1, (t + 1) * 32);
            asm volatile("s_waitcnt vmcnt(3)" ::: "memory");
        } else {
            asm volatile("s_waitcnt vmcnt(0)" ::: "memory");
        }
        __builtin_amdgcn_s_barrier();
        __builtin_amdgcn_sched_barrier(0);
        half8 ah[2], bh[4];
#pragma unroll
        for (int m = 0; m < 2; ++m)
            ah[m] = *(const half8*)&ldsA[cur][((wr * 2 + m) * 64 + l) * 8];
#pragma unroll
        for (int n = 0; n < 4; ++n)
            bh[n] = *(const half8*)&ldsB[cur][((wc * 4 + n) * 64 + l) * 8];
#pragma unroll
        for (int m = 0; m < 2; ++m)
#pragma unroll
            for (int n = 0; n < 4; ++n)
                acc[m][n] = __builtin_amdgcn_mfma_f32_16x16x32_f16(ah[m], bh[n], acc[m][n], 0, 0, 0);
        __builtin_amdgcn_s_barrier();
    }

    const int lr = (l >> 4) * 4, lc = l & 15;
#pragma unroll
    for (int m = 0; m < 2; ++m) {
#pragma unroll
        for (int n = 0; n < 4; ++n) {
#pragma unroll
            for (int j = 0; j < 4; ++j) {
                const int row = bm + wr * 32 + m * 16 + lr + j;
                const int col = wc * 64 + n * 16 + lc;
                const float v = acc[m][n][j];
                OUT[(size_t)bz * NN * FF + (size_t)row * FF + col] =
                    v > 0.f ? v : __expf(v) - 1.f;
            }
        }
    }
}

extern "C" void kernel_launch(void* const* d_in, const int* in_sizes, int n_in,
                              void* d_out, int out_size, void* d_ws, size_t ws_size,
                              hipStream_t stream) {
    const float* h = (const float*)d_in[0];
    const float* W = (const float*)d_in[1];
    const float* a = (const float*)d_in[2];
    const float* A0 = (const float*)d_in[3];
    const float* A2 = (const float*)d_in[4];
    float* out = (float*)d_out;

    char* ws = (char*)d_ws;
    size_t ofs = 0;
    auto alloc = [&](size_t bytes) -> void* {
        void* p = ws + ofs;
        ofs = (ofs + bytes + 255) & ~(size_t)255;
        return p;
    };
    float* u12 = (float*)alloc(2 * FF * sizeof(float));
    float* Wh12 = (float*)alloc(2 * (size_t)BB * NN * sizeof(float));
    u16* WhThi = (u16*)alloc((size_t)BB * FF * NN * 2);
    u16* A0hi = (u16*)alloc((size_t)K4 * NN * 2);
    u16* A0lo = (u16*)alloc((size_t)K4 * NN * 2);
    u16* A2hi = (u16*)alloc((size_t)NN * K4 * 2);
    u16* A2lo = (u16*)alloc((size_t)NN * K4 * 2);

    // per-batch chunk bytes: S hi/lo + packed ADJ (Att hi aliases dead S)
    const size_t per_b = (size_t)NN * K4 * 2 * 2 + (size_t)NN * NN * 4;
    int cb = BB;
    while (cb > 1 && ofs + (size_t)cb * per_b + 8192 > ws_size) cb >>= 1;
    u16* Shi = (u16*)alloc((size_t)cb * NN * K4 * 2);
    u16* Slo = (u16*)alloc((size_t)cb * NN * K4 * 2);
    u32* ADJ = (u32*)alloc((size_t)cb * NN * NN * 4);
    u16* AttHi = Shi;  // alias: S dead after g2

    k_u<<<1, 128, 0, stream>>>(W, a, u12);
    k_wh12<<<BB * NN, 128, 0, stream>>>(h, u12, Wh12);
    k_whT<<<dim3((BB * NN) / 64, FF / 64), 256, 0, stream>>>(W, h, WhThi);
    k_split<<<(K4 * NN / 4 + 255) / 256, 256, 0, stream>>>(A0, A0hi, A0lo, K4 * NN / 4);
    k_split<<<(NN * K4 / 4 + 255) / 256, 256, 0, stream>>>(A2, A2hi, A2lo, NN * K4 / 4);

    for (int c0 = 0; c0 < BB; c0 += cb) {
        const int c = (BB - c0) < cb ? (BB - c0) : cb;
        const int mb1 = c * 4;   // g1: M = c*512, BM = 128 -> grid mb1 * 8
        const int mb2 = c * 4;   // g2: BM = 128, BN = 256 -> grid mb2 * 2
        // S = sigmoid(E @ A0^T), E on the fly, single-buffered high-occupancy
        k_g1<<<mb1 * (K4 / 256), 512, 0, stream>>>(Wh12, c0, A0hi, A0lo, Shi, Slo, mb1);
        // adj = S @ A2^T + e; mask -> packed ADJ (r8 schedule)
        k_g2<<<mb2 * (NN / 256), 512, 0, stream>>>(Shi, Slo, A2hi, A2lo, Wh12, c0, ADJ, mb2);
        k_softmax2<<<c * NN, 256, 0, stream>>>(ADJ, AttHi);
        // out = elu(att @ Wh), single-term fp16
        k_pv<<<dim3(1, NN / 64, c), 256, 0, stream>>>(
            AttHi, WhThi + (size_t)c0 * FF * NN, out + (size_t)c0 * NN * FF);
    }
}

// Round 15
// 272.210 us; speedup vs baseline: 1.1623x; 1.0113x over previous
//
#include <hip/hip_runtime.h>

#define BB 32
#define NN 512
#define FF 128
#define K4 2048
#define ALPHA 0.2f
#define THRESH 0.6f
#define NEGINF -9e15f

typedef unsigned short u16;
typedef unsigned int u32;
typedef _Float16 f16;
typedef __attribute__((ext_vector_type(8))) _Float16 half8;
typedef __attribute__((ext_vector_type(4))) float f32x4;

union U16F { u16 u; f16 h; };
__device__ __forceinline__ u16 hbits(f16 h) { U16F x; x.h = h; return x.u; }
__device__ __forceinline__ float htof(u16 u) { U16F x; x.u = u; return (float)x.h; }
__device__ __forceinline__ void split2(float v, u16& hi, u16& lo) {
    f16 h = (f16)v;
    f16 l = (f16)(v - (float)h);
    hi = hbits(h);
    lo = hbits(l);
}
__device__ __forceinline__ float lrelu(float x) { return fmaxf(x, ALPHA * x); }

__device__ __forceinline__ void gload16(const void* g, void* l) {
    __builtin_amdgcn_global_load_lds(
        (__attribute__((address_space(1))) const unsigned int*)(unsigned long long)g,
        (__attribute__((address_space(3))) unsigned int*)(unsigned int)(unsigned long long)l,
        16, 0, 0);
}

// u1[f] = sum_g W[g,f]*a[g];  u2[f] = sum_g W[g,f]*a[F+g]
__global__ void k_u(const float* __restrict__ W, const float* __restrict__ a,
                    float* __restrict__ u12) {
    int f = threadIdx.x;
    float s1 = 0.f, s2 = 0.f;
    for (int g = 0; g < FF; ++g) {
        float w = W[g * FF + f];
        s1 += w * a[g];
        s2 += w * a[FF + g];
    }
    u12[f] = s1;
    u12[FF + f] = s2;
}

// Wh1[row] = h[row,:]·u1 ; Wh2[row] = h[row,:]·u2   (flat row = b*N+n)
__global__ void k_wh12(const float* __restrict__ h, const float* __restrict__ u12,
                       float* __restrict__ Wh12) {
    int row = blockIdx.x;
    int f = threadIdx.x;  // 128
    float hv = h[(size_t)row * FF + f];
    float p1 = hv * u12[f], p2 = hv * u12[FF + f];
#pragma unroll
    for (int o = 1; o < 64; o <<= 1) {
        p1 += __shfl_xor(p1, o, 64);
        p2 += __shfl_xor(p2, o, 64);
    }
    __shared__ float s1[2], s2[2];
    int w = f >> 6;
    if ((f & 63) == 0) { s1[w] = p1; s2[w] = p2; }
    __syncthreads();
    if (f == 0) {
        Wh12[row] = s1[0] + s1[1];
        Wh12[BB * NN + row] = s2[0] + s2[1];
    }
}

// WhT[b][f][n] = (h@W^T)[b][n][f], fp16 hi only (PV tolerates 2^-11 on Wh).
__global__ __launch_bounds__(256) void k_whT(const float* __restrict__ W,
                                             const float* __restrict__ h,
                                             u16* __restrict__ Thi) {
    const int bm = blockIdx.y * 64, bn = blockIdx.x * 64;
    __shared__ float As[32][68];
    __shared__ float Bs[32][68];
    int tid = threadIdx.x;
    int tx = tid & 15, ty = tid >> 4;
    float acc[4][4] = {{0.f}};
    int r = tid >> 3, q = tid & 7;
    const float* Ap = W + (size_t)(bm + r) * FF + q * 4;
    const float* Bp = h + (size_t)(bn + r) * FF + q * 4;
    for (int k0 = 0; k0 < FF; k0 += 32) {
        float4 a0 = *(const float4*)(Ap + k0);
        float4 a1 = *(const float4*)(Ap + k0 + 32 * FF);
        float4 b0 = *(const float4*)(Bp + k0);
        float4 b1 = *(const float4*)(Bp + k0 + 32 * FF);
        __syncthreads();
        As[q * 4 + 0][r] = a0.x; As[q * 4 + 1][r] = a0.y;
        As[q * 4 + 2][r] = a0.z; As[q * 4 + 3][r] = a0.w;
        As[q * 4 + 0][r + 32] = a1.x; As[q * 4 + 1][r + 32] = a1.y;
        As[q * 4 + 2][r + 32] = a1.z; As[q * 4 + 3][r + 32] = a1.w;
        Bs[q * 4 + 0][r] = b0.x; Bs[q * 4 + 1][r] = b0.y;
        Bs[q * 4 + 2][r] = b0.z; Bs[q * 4 + 3][r] = b0.w;
        Bs[q * 4 + 0][r + 32] = b1.x; Bs[q * 4 + 1][r + 32] = b1.y;
        Bs[q * 4 + 2][r + 32] = b1.z; Bs[q * 4 + 3][r + 32] = b1.w;
        __syncthreads();
#pragma unroll
        for (int kk = 0; kk < 32; ++kk) {
            float av[4], bv[4];
            *(float4*)av = *(const float4*)&As[kk][ty * 4];
            *(float4*)bv = *(const float4*)&Bs[kk][tx * 4];
#pragma unroll
            for (int i = 0; i < 4; ++i)
#pragma unroll
                for (int j = 0; j < 4; ++j) acc[i][j] = fmaf(av[i], bv[j], acc[i][j]);
        }
    }
#pragma unroll
    for (int i = 0; i < 4; ++i) {
        int f = bm + ty * 4 + i;
#pragma unroll
        for (int j = 0; j < 4; ++j) {
            int mg = bn + tx * 4 + j;
            size_t idx = ((size_t)(mg >> 9) * FF + f) * NN + (mg & 511);
            Thi[idx] = hbits((f16)acc[i][j]);
        }
    }
}

// fp32 -> fp16 hi/lo split for A0 and A2 in one launch (n4 each, A0 first)
__global__ void k_split2(const float* __restrict__ X0, u16* __restrict__ Hi0,
                         u16* __restrict__ Lo0, const float* __restrict__ X1,
                         u16* __restrict__ Hi1, u16* __restrict__ Lo1, int n4) {
    int i = blockIdx.x * 256 + threadIdx.x;
    const float* X;
    u16 *Hi, *Lo;
    if (i >= n4) {
        i -= n4;
        if (i >= n4) return;
        X = X1; Hi = Hi1; Lo = Lo1;
    } else {
        X = X0; Hi = Hi0; Lo = Lo0;
    }
    float4 v = *(const float4*)(X + (size_t)i * 4);
    ushort4 hh, ll;
    split2(v.x, hh.x, ll.x);
    split2(v.y, hh.y, ll.y);
    split2(v.z, hh.z, ll.z);
    split2(v.w, hh.w, ll.w);
    *(ushort4*)(Hi + (size_t)i * 4) = hh;
    *(ushort4*)(Lo + (size_t)i * 4) = ll;
}

// GEMM1: S = sigmoid(E @ A0^T), E generated on the fly from Wh12.
// Tile 128x256 (MxN), BK=32, 512 threads (8 waves: 2m x 4n), SINGLE-buffered
// 48KB LDS -> 3 blocks/CU capacity; grid 32*c -> 2 resident blocks/CU.
__global__ __launch_bounds__(512) void k_g1(const float* __restrict__ Wh12, int c0,
                                            const u16* __restrict__ Bhi,
                                            const u16* __restrict__ Blo,
                                            u16* __restrict__ Shi, u16* __restrict__ Slo,
                                            int mblocks) {
    __shared__ __align__(16) u16 ldsA[8192];   // hi [0..4095], lo [4096..8191]
    __shared__ __align__(16) u16 ldsB[16384];  // hi [0..8191], lo [8192..16383]
    __shared__ float wh1s[128];
    __shared__ float wh2s[512];
    const int tid = threadIdx.x;
    const int l = tid & 63, w = tid >> 6;
    const int wm = w >> 2, wn = w & 3;
    const int nwg = gridDim.x, q = nwg >> 3;
    const int wg = (blockIdx.x & 7) * q + (blockIdx.x >> 3);
    const int nb = wg / mblocks, mb = wg % mblocks;
    const int bm = mb * 128, bn = nb * 256;
    const int bglob = c0 + (bm >> 9);

    if (tid < 128) wh1s[tid] = Wh12[(size_t)c0 * NN + bm + tid];
    if (tid < 512) wh2s[tid] = Wh12[BB * NN + (size_t)bglob * NN + tid];

    f32x4 acc[4][4];
#pragma unroll
    for (int m = 0; m < 4; ++m)
#pragma unroll
        for (int n = 0; n < 4; ++n) acc[m][n] = (f32x4){0.f, 0.f, 0.f, 0.f};

    const int gb0 = w * 2, gb1 = w * 2 + 1;
    const size_t rb0 = (size_t)(bn + gb0 * 16 + (l & 15)) * NN + ((l >> 4) * 8);
    const size_t rb1 = (size_t)(bn + gb1 * 16 + (l & 15)) * NN + ((l >> 4) * 8);
    const int arow = (tid >> 6) * 16 + (l & 15);
    const int akc = (l >> 4) * 8;

    __syncthreads();  // wh arrays ready

    const float myw1 = wh1s[arow];

    for (int t = 0; t < 16; ++t) {
        const int k0 = t * 32;
        gload16(Bhi + rb0 + k0, &ldsB[gb0 * 512]);
        gload16(Bhi + rb1 + k0, &ldsB[gb1 * 512]);
        gload16(Blo + rb0 + k0, &ldsB[8192 + gb0 * 512]);
        gload16(Blo + rb1 + k0, &ldsB[8192 + gb1 * 512]);
        {
            const int kc = k0 + akc;
            float w2v[8];
            *(float4*)&w2v[0] = *(const float4*)&wh2s[kc];
            *(float4*)&w2v[4] = *(const float4*)&wh2s[kc + 4];
            u32 hh[4], llv[4];
#pragma unroll
            for (int jj = 0; jj < 4; ++jj) {
                float e0 = lrelu(myw1 + w2v[2 * jj]);
                float e1 = lrelu(myw1 + w2v[2 * jj + 1]);
                u16 h0, l0, h1, l1;
                split2(e0, h0, l0);
                split2(e1, h1, l1);
                hh[jj] = (u32)h0 | ((u32)h1 << 16);
                llv[jj] = (u32)l0 | ((u32)l1 << 16);
            }
            *(uint4*)&ldsA[tid * 8] = make_uint4(hh[0], hh[1], hh[2], hh[3]);
            *(uint4*)&ldsA[4096 + tid * 8] = make_uint4(llv[0], llv[1], llv[2], llv[3]);
        }
        __syncthreads();
        half8 bh[4], bl[4];
#pragma unroll
        for (int n = 0; n < 4; ++n) {
            const int gB = wn * 4 + n;
            bh[n] = *(const half8*)&ldsB[(gB * 64 + l) * 8];
            bl[n] = *(const half8*)&ldsB[8192 + (gB * 64 + l) * 8];
        }
#pragma unroll
        for (int m = 0; m < 4; ++m) {
            const int gA = wm * 4 + m;
            half8 ah = *(const half8*)&ldsA[(gA * 64 + l) * 8];
            half8 al = *(const half8*)&ldsA[4096 + (gA * 64 + l) * 8];
#pragma unroll
            for (int n = 0; n < 4; ++n)
                acc[m][n] = __builtin_amdgcn_mfma_f32_16x16x32_f16(ah, bh[n], acc[m][n], 0, 0, 0);
#pragma unroll
            for (int n = 0; n < 4; ++n)
                acc[m][n] = __builtin_amdgcn_mfma_f32_16x16x32_f16(al, bh[n], acc[m][n], 0, 0, 0);
#pragma unroll
            for (int n = 0; n < 4; ++n)
                acc[m][n] = __builtin_amdgcn_mfma_f32_16x16x32_f16(ah, bl[n], acc[m][n], 0, 0, 0);
        }
        __syncthreads();
    }

    const int lr = (l >> 4) * 4, lc = l & 15;
#pragma unroll
    for (int m = 0; m < 4; ++m) {
#pragma unroll
        for (int n = 0; n < 4; ++n) {
#pragma unroll
            for (int j = 0; j < 4; ++j) {
                const int row = bm + wm * 64 + m * 16 + lr + j;
                const int col = bn + wn * 64 + n * 16 + lc;
                const float s = 1.f / (1.f + __expf(-acc[m][n][j]));
                u16 hi, lo;
                split2(s, hi, lo);
                const size_t idx = (size_t)row * K4 + col;
                Shi[idx] = hi;
                Slo[idx] = lo;
            }
        }
    }
}

// GEMM2 (r8 schedule, nb-INNER decode): adj = S @ A2^T + e; mask -> packed ADJ.
// Tile 128x256, BK=32, 8 waves, 96 KB LDS, counted vmcnt(6) depth-2.
// nb-inner: the two n-blocks sharing an S row-panel are adjacent in the
// XCD-chunked order -> co-resident -> second S read is L2-hit (~200cy vs 900).
__global__ __launch_bounds__(512, 2) void k_g2(const u16* __restrict__ Ahi,
                                               const u16* __restrict__ Alo,
                                               const u16* __restrict__ Bhi,
                                               const u16* __restrict__ Blo,
                                               const float* __restrict__ Wh12, int c0,
                                               u32* __restrict__ ADJ, int mblocks) {
    __shared__ __align__(16) u16 ldsA[2][2][4096];
    __shared__ __align__(16) u16 ldsB[2][2][8192];
    const int tid = threadIdx.x;
    const int l = tid & 63, w = tid >> 6;
    const int nwg = gridDim.x, q = nwg >> 3;
    const int wg = ((int)blockIdx.x & 7) * q + ((int)blockIdx.x >> 3);
    const int mb = wg >> 1, nb = wg & 1;  // nb-inner: S-panel twins adjacent
    const int bm = mb * 128, bn = nb * 256;

    auto STAGE = [&](int buf, int k0) {
        const size_t ra = (size_t)(bm + w * 16 + (l & 15)) * K4 + k0 + ((l >> 4) * 8);
        gload16(Ahi + ra, &ldsA[buf][0][w * 512]);
        gload16(Alo + ra, &ldsA[buf][1][w * 512]);
#pragma unroll
        for (int i = 0; i < 2; ++i) {
            const int g = w * 2 + i;
            const size_t rb = (size_t)(bn + g * 16 + (l & 15)) * K4 + k0 + ((l >> 4) * 8);
            gload16(Bhi + rb, &ldsB[buf][0][g * 512]);
            gload16(Blo + rb, &ldsB[buf][1][g * 512]);
        }
    };

    f32x4 acc[4][4];
#pragma unroll
    for (int m = 0; m < 4; ++m)
#pragma unroll
        for (int n = 0; n < 4; ++n) acc[m][n] = (f32x4){0.f, 0.f, 0.f, 0.f};

    STAGE(0, 0);
    for (int t = 0; t < 64; ++t) {
        const int cur = t & 1;
        if (t < 63) {
            STAGE(cur ^ 1, (t + 1) * 32);
            asm volatile("s_waitcnt vmcnt(6)" ::: "memory");
        } else {
            asm volatile("s_waitcnt vmcnt(0)" ::: "memory");
        }
        __builtin_amdgcn_s_barrier();
        __builtin_amdgcn_sched_barrier(0);
        half8 bh[4], bl[4];
#pragma unroll
        for (int n = 0; n < 4; ++n) {
            const int gB = (w & 3) * 4 + n;
            bh[n] = *(const half8*)&ldsB[cur][0][(gB * 64 + l) * 8];
            bl[n] = *(const half8*)&ldsB[cur][1][(gB * 64 + l) * 8];
        }
        __builtin_amdgcn_s_setprio(1);
#pragma unroll
        for (int m = 0; m < 4; ++m) {
            const int gA = (w >> 2) * 4 + m;
            half8 ah = *(const half8*)&ldsA[cur][0][(gA * 64 + l) * 8];
            half8 al = *(const half8*)&ldsA[cur][1][(gA * 64 + l) * 8];
#pragma unroll
            for (int n = 0; n < 4; ++n)
                acc[m][n] = __builtin_amdgcn_mfma_f32_16x16x32_f16(ah, bh[n], acc[m][n], 0, 0, 0);
#pragma unroll
            for (int n = 0; n < 4; ++n)
                acc[m][n] = __builtin_amdgcn_mfma_f32_16x16x32_f16(al, bh[n], acc[m][n], 0, 0, 0);
#pragma unroll
            for (int n = 0; n < 4; ++n)
                acc[m][n] = __builtin_amdgcn_mfma_f32_16x16x32_f16(ah, bl[n], acc[m][n], 0, 0, 0);
        }
        __builtin_amdgcn_s_setprio(0);
        __builtin_amdgcn_sched_barrier(0);
        __builtin_amdgcn_s_barrier();
    }

    const int bglob = c0 + (bm >> 9);
    const float* wh2p = Wh12 + BB * NN + (size_t)bglob * NN;
    const int lr = (l >> 4) * 4, lc = l & 15;
#pragma unroll
    for (int m = 0; m < 4; ++m) {
#pragma unroll
        for (int n = 0; n < 4; ++n) {
#pragma unroll
            for (int j = 0; j < 4; ++j) {
                const int row = bm + (w >> 2) * 64 + m * 16 + lr + j;
                const int col = bn + (w & 3) * 64 + n * 16 + lc;
                const float e = lrelu(Wh12[(size_t)c0 * NN + row] + wh2p[col]);
                u32 pk = 0xFFFFFFFFu;
                if (e + acc[m][n][j] > THRESH) {
                    u16 hi, lo;
                    split2(e, hi, lo);
                    pk = (u32)hi | ((u32)lo << 16);
                }
                ADJ[(size_t)row * NN + col] = pk;
            }
        }
    }
}

// softmax rows of packed ADJ, write att as fp16 hi ONLY (PV error budget).
__global__ __launch_bounds__(256) void k_softmax2(const u32* __restrict__ ADJ,
                                                  u16* __restrict__ Hi) {
    const size_t row = blockIdx.x;
    const u32* p = ADJ + row * NN;
    const int t = threadIdx.x;
    u32 w0 = p[t], w1 = p[t + 256];
    float v0 = (w0 == 0xFFFFFFFFu) ? NEGINF : htof((u16)(w0 & 0xFFFF)) + htof((u16)(w0 >> 16));
    float v1 = (w1 == 0xFFFFFFFFu) ? NEGINF : htof((u16)(w1 & 0xFFFF)) + htof((u16)(w1 >> 16));
    float m = fmaxf(v0, v1);
#pragma unroll
    for (int o = 1; o < 64; o <<= 1) m = fmaxf(m, __shfl_xor(m, o, 64));
    __shared__ float red[4], red2[4];
    int w = t >> 6;
    if ((t & 63) == 0) red[w] = m;
    __syncthreads();
    m = fmaxf(fmaxf(red[0], red[1]), fmaxf(red[2], red[3]));
    float e0 = __expf(v0 - m), e1 = __expf(v1 - m);
    float s = e0 + e1;
#pragma unroll
    for (int o = 1; o < 64; o <<= 1) s += __shfl_xor(s, o, 64);
    if ((t & 63) == 0) red2[w] = s;
    __syncthreads();
    s = red2[0] + red2[1] + red2[2] + red2[3];
    float inv = 1.f / s;
    Hi[row * NN + t] = hbits((f16)(e0 * inv));
    Hi[row * NN + t + 256] = hbits((f16)(e1 * inv));
}

// PV: out = elu(att @ Wh), single-term fp16 (att_hi x Wh_hi).
// BM=64, 256 threads / 4 waves, wave-tile 32x64, 24KB LDS, vmcnt(3) depth-2.
__global__ __launch_bounds__(256) void k_pv(const u16* __restrict__ Ahi,
                                            const u16* __restrict__ Bhi,
                                            float* __restrict__ OUT) {
    __shared__ __align__(16) u16 ldsA[2][2048];  // 64x32
    __shared__ __align__(16) u16 ldsB[2][4096];  // 128x32
    const int tid = threadIdx.x;
    const int l = tid & 63, w = tid >> 6;  // 4 waves
    const int wr = w >> 1, wc = w & 1;
    const int bz = blockIdx.z;
    const int bm = blockIdx.y * 64;

    const u16* Ap = Ahi + (size_t)bz * NN * NN;
    const u16* Bp = Bhi + (size_t)bz * FF * NN;

    const size_t offA = (size_t)(bm + w * 16 + (l & 15)) * NN + (l >> 4) * 8;
    const size_t offB0 = (size_t)((w * 2 + 0) * 16 + (l & 15)) * NN + (l >> 4) * 8;
    const size_t offB1 = (size_t)((w * 2 + 1) * 16 + (l & 15)) * NN + (l >> 4) * 8;

    auto STAGE = [&](int buf, int kk) {
        gload16(Ap + offA + kk, &ldsA[buf][w * 512]);
        gload16(Bp + offB0 + kk, &ldsB[buf][(w * 2 + 0) * 512]);
        gload16(Bp + offB1 + kk, &ldsB[buf][(w * 2 + 1) * 512]);
    };

    f32x4 acc[2][4];
#pragma unroll
    for (int m = 0; m < 2; ++m)
#pragma unroll
        for (int n = 0; n < 4; ++n) acc[m][n] = (f32x4){0.f, 0.f, 0.f, 0.f};

    STAGE(0, 0);
    for (int t = 0; t < 16; ++t) {
        const int cur = t & 1;
        if (t + 1 < 16) {
            STAGE(cur ^ 1, (t + 1) * 32);
            asm volatile("s_waitcnt vmcnt(3)" ::: "memory");
        } else {
            asm volatile("s_waitcnt vmcnt(0)" ::: "memory");
        }
        __builtin_amdgcn_s_barrier();
        __builtin_amdgcn_sched_barrier(0);
        half8 ah[2], bh[4];
#pragma unroll
        for (int m = 0; m < 2; ++m)
            ah[m] = *(const half8*)&ldsA[cur][((wr * 2 + m) * 64 + l) * 8];
#pragma unroll
        for (int n = 0; n < 4; ++n)
            bh[n] = *(const half8*)&ldsB[cur][((wc * 4 + n) * 64 + l) * 8];
#pragma unroll
        for (int m = 0; m < 2; ++m)
#pragma unroll
            for (int n = 0; n < 4; ++n)
                acc[m][n] = __builtin_amdgcn_mfma_f32_16x16x32_f16(ah[m], bh[n], acc[m][n], 0, 0, 0);
        __builtin_amdgcn_s_barrier();
    }

    const int lr = (l >> 4) * 4, lc = l & 15;
#pragma unroll
    for (int m = 0; m < 2; ++m) {
#pragma unroll
        for (int n = 0; n < 4; ++n) {
#pragma unroll
            for (int j = 0; j < 4; ++j) {
                const int row = bm + wr * 32 + m * 16 + lr + j;
                const int col = wc * 64 + n * 16 + lc;
                const float v = acc[m][n][j];
                OUT[(size_t)bz * NN * FF + (size_t)row * FF + col] =
                    v > 0.f ? v : __expf(v) - 1.f;
            }
        }
    }
}

extern "C" void kernel_launch(void* const* d_in, const int* in_sizes, int n_in,
                              void* d_out, int out_size, void* d_ws, size_t ws_size,
                              hipStream_t stream) {
    const float* h = (const float*)d_in[0];
    const float* W = (const float*)d_in[1];
    const float* a = (const float*)d_in[2];
    const float* A0 = (const float*)d_in[3];
    const float* A2 = (const float*)d_in[4];
    float* out = (float*)d_out;

    char* ws = (char*)d_ws;
    size_t ofs = 0;
    auto alloc = [&](size_t bytes) -> void* {
        void* p = ws + ofs;
        ofs = (ofs + bytes + 255) & ~(size_t)255;
        return p;
    };
    float* u12 = (float*)alloc(2 * FF * sizeof(float));
    float* Wh12 = (float*)alloc(2 * (size_t)BB * NN * sizeof(float));
    u16* WhThi = (u16*)alloc((size_t)BB * FF * NN * 2);
    u16* A0hi = (u16*)alloc((size_t)K4 * NN * 2);
    u16* A0lo = (u16*)alloc((size_t)K4 * NN * 2);
    u16* A2hi = (u16*)alloc((size_t)NN * K4 * 2);
    u16* A2lo = (u16*)alloc((size_t)NN * K4 * 2);

    // per-batch chunk bytes: S hi/lo + packed ADJ (Att hi aliases dead S)
    const size_t per_b = (size_t)NN * K4 * 2 * 2 + (size_t)NN * NN * 4;
    int cb = BB;
    while (cb > 1 && ofs + (size_t)cb * per_b + 8192 > ws_size) cb >>= 1;
    u16* Shi = (u16*)alloc((size_t)cb * NN * K4 * 2);
    u16* Slo = (u16*)alloc((size_t)cb * NN * K4 * 2);
    u32* ADJ = (u32*)alloc((size_t)cb * NN * NN * 4);
    u16* AttHi = Shi;  // alias: S dead after g2

    k_u<<<1, 128, 0, stream>>>(W, a, u12);
    k_wh12<<<BB * NN, 128, 0, stream>>>(h, u12, Wh12);
    k_whT<<<dim3((BB * NN) / 64, FF / 64), 256, 0, stream>>>(W, h, WhThi);
    k_split2<<<(2 * (K4 * NN / 4) + 255) / 256, 256, 0, stream>>>(
        A0, A0hi, A0lo, A2, A2hi, A2lo, K4 * NN / 4);

    for (int c0 = 0; c0 < BB; c0 += cb) {
        const int c = (BB - c0) < cb ? (BB - c0) : cb;
        const int mb1 = c * 4;   // g1: M = c*512, BM = 128 -> grid mb1 * 8
        const int mb2 = c * 4;   // g2: BM = 128, BN = 256 -> grid mb2 * 2
        // S = sigmoid(E @ A0^T), E on the fly, single-buffered high-occupancy
        k_g1<<<mb1 * (K4 / 256), 512, 0, stream>>>(Wh12, c0, A0hi, A0lo, Shi, Slo, mb1);
        // adj = S @ A2^T + e; mask -> packed ADJ (r8 schedule, nb-inner)
        k_g2<<<mb2 * (NN / 256), 512, 0, stream>>>(Shi, Slo, A2hi, A2lo, Wh12, c0, ADJ, mb2);
        k_softmax2<<<c * NN, 256, 0, stream>>>(ADJ, AttHi);
        // out = elu(att @ Wh), single-term fp16
        k_pv<<<dim3(1, NN / 64, c), 256, 0, stream>>>(
            AttHi, WhThi + (size_t)c0 * FF * NN, out + (size_t)c0 * NN * FF);
    }
}